// Round 2
// baseline (176.971 us; speedup 1.0000x reference)
//
#include <hip/hip_runtime.h>
#include <hip/hip_bf16.h>

typedef __bf16 bf16_t;
typedef __bf16 bf16x8 __attribute__((ext_vector_type(8)));
typedef float  f32x4  __attribute__((ext_vector_type(4)));

// ---------------- problem constants ----------------
#define NB 4096
#define IN_DIM 256
#define HID 512
#define SUB 256
#define GRID_ 32

// ---------------- trig helpers (input: revolutions, pre-reduced to [0,1)) ----
__device__ __forceinline__ float cos_rev(float rev) {
#if __has_builtin(__builtin_amdgcn_cosf)
  return __builtin_amdgcn_cosf(rev);
#else
  return __cosf(rev * 6.283185307179586f);
#endif
}
__device__ __forceinline__ float sin_rev(float rev) {
#if __has_builtin(__builtin_amdgcn_sinf)
  return __builtin_amdgcn_sinf(rev);
#else
  return __sinf(rev * 6.283185307179586f);
#endif
}

// ---------------- workspace layout (bytes), total ~57 MB ----------------
// Overlays (stream-ordered lifetimes):
//   GATES dead after k_cell -> AGG and P live inside GATES region.
//   FCB dead after k_fourier -> O lives in FCB region.
#define O_XHI   0ull
#define O_XLO   2097152ull
#define O_H0    4194304ull
#define O_S0H   8388608ull
#define O_S0L   10485760ull
#define O_FCB   12582912ull
#define O_O     12582912ull
#define O_KT    20971520ull
#define O_RKT   21757952ull
#define O_AWT   23330816ull
#define O_KXH   23592960ull
#define O_KXL   23724032ull
#define O_KHH   23855104ull
#define O_KHL   23986176ull
#define O_TC    24117248ull
#define O_SOB   32505856ull
#define O_GATES 34603008ull
#define O_AGG   34603008ull
#define O_P     38797312ull
// end of GATES region = 59768832 (~57 MB)

// ---------------- conversion: f32 -> bf16 (hi [, lo residual]) ----------------
template<bool LO>
__global__ __launch_bounds__(256) void k_conv(const float* __restrict__ src,
                                              bf16_t* __restrict__ hi,
                                              bf16_t* __restrict__ lo, int n) {
  int stride = gridDim.x * blockDim.x;
  for (int i = blockIdx.x * blockDim.x + threadIdx.x; i < n; i += stride) {
    float f = src[i];
    bf16_t h = (bf16_t)f;
    hi[i] = h;
    if (LO) lo[i] = (bf16_t)(f - (float)h);
  }
}

// ---------------- transpose-convert: f32 [R][C] -> bf16 [C][R] ----------------
template<bool LO>
__global__ __launch_bounds__(256) void k_tconv(const float* __restrict__ src,
                                               bf16_t* __restrict__ hi,
                                               bf16_t* __restrict__ lo,
                                               int R, int C) {
  __shared__ float t[32][33];
  int c0 = blockIdx.x * 32, r0 = blockIdx.y * 32;
  int tx = threadIdx.x & 31, ty = threadIdx.x >> 5;  // 32 x 8
#pragma unroll
  for (int rr = 0; rr < 4; rr++) {
    int r = ty + rr * 8;
    t[r][tx] = src[(size_t)(r0 + r) * C + c0 + tx];
  }
  __syncthreads();
#pragma unroll
  for (int rr = 0; rr < 4; rr++) {
    int cl = ty + rr * 8;
    float f = t[tx][cl];
    bf16_t h = (bf16_t)f;
    size_t oi = (size_t)(c0 + cl) * R + r0 + tx;
    hi[oi] = h;
    if (LO) lo[oi] = (bf16_t)(f - (float)h);
  }
}

// ---------------- generic multi-pass bf16 MFMA GEMM ----------------
// C[M,N] = sum_passes A_p[M,K_p] * B_p[K_p,N]   (B given pre-transposed [N][K])
// epilogue: act==1 -> sigmoid(acc + bias[n]); act==0 -> acc (bias optional)
struct Pass { const bf16_t* A; const bf16_t* Bt; int K; int lda; int ldbt; };
struct GArgs {
  Pass p[6]; int np;
  int N;                    // M implied by grid
  const float* bias;        // may be null
  int act;
  float* out; int ldout;
};

__global__ __launch_bounds__(512) void k_gemm(GArgs g) {
  __shared__ bf16_t smA[128 * 72];
  __shared__ bf16_t smB[128 * 72];
  const int tid = threadIdx.x;
  const int m0 = blockIdx.y * 128, n0 = blockIdx.x * 128;
  const int wv = tid >> 6, lane = tid & 63;
  const int wm = wv >> 2, wn = wv & 3;          // 2x4 waves, each 64x32
  const int lr = lane & 15, lk = (lane >> 4) * 8;

  f32x4 acc[4][2];
#pragma unroll
  for (int i = 0; i < 4; i++)
#pragma unroll
    for (int j = 0; j < 2; j++) acc[i][j] = f32x4{0.f, 0.f, 0.f, 0.f};

  for (int ps = 0; ps < g.np; ps++) {
    const bf16_t* A = g.p[ps].A;
    const bf16_t* Bt = g.p[ps].Bt;
    const int K = g.p[ps].K, lda = g.p[ps].lda, ldbt = g.p[ps].ldbt;
    for (int k0 = 0; k0 < K; k0 += 64) {
      bf16x8 ar[2], br[2];
#pragma unroll
      for (int r = 0; r < 2; r++) {
        int task = tid + r * 512;       // 1024 tasks: 128 rows x 8 segs
        int row = task >> 3, seg = task & 7;
        ar[r] = *(const bf16x8*)(A  + (size_t)(m0 + row) * lda  + k0 + seg * 8);
        br[r] = *(const bf16x8*)(Bt + (size_t)(n0 + row) * ldbt + k0 + seg * 8);
      }
      __syncthreads();
#pragma unroll
      for (int r = 0; r < 2; r++) {
        int task = tid + r * 512;
        int row = task >> 3, seg = task & 7;
        *(bf16x8*)(smA + row * 72 + seg * 8) = ar[r];
        *(bf16x8*)(smB + row * 72 + seg * 8) = br[r];
      }
      __syncthreads();
#pragma unroll
      for (int ks = 0; ks < 2; ks++) {
        bf16x8 af[4], bfr[2];
#pragma unroll
        for (int i = 0; i < 4; i++)
          af[i] = *(const bf16x8*)(smA + (wm * 64 + i * 16 + lr) * 72 + ks * 32 + lk);
#pragma unroll
        for (int j = 0; j < 2; j++)
          bfr[j] = *(const bf16x8*)(smB + (wn * 32 + j * 16 + lr) * 72 + ks * 32 + lk);
#pragma unroll
        for (int i = 0; i < 4; i++)
#pragma unroll
          for (int j = 0; j < 2; j++)
            acc[i][j] = __builtin_amdgcn_mfma_f32_16x16x32_bf16(af[i], bfr[j], acc[i][j], 0, 0, 0);
      }
    }
  }
  // epilogue
#pragma unroll
  for (int i = 0; i < 4; i++) {
#pragma unroll
    for (int j = 0; j < 2; j++) {
      int col = n0 + wn * 32 + j * 16 + lr;
      float bb = g.bias ? g.bias[col] : 0.f;
#pragma unroll
      for (int r = 0; r < 4; r++) {
        int row = m0 + wm * 64 + i * 16 + (lane >> 4) * 4 + r;
        float v = acc[i][j][r] + bb;
        if (g.act == 1) v = 1.f / (1.f + __expf(-v));
        g.out[(size_t)row * g.ldout + col] = v;
      }
    }
  }
}

// ---------------- Fourier-KAN GEMM ----------------
// P_q[b,o] = sum_{i in q-range} sum_g cos(z[b,i]*k_g)*fc[0,o,i,g] + sin(...)*fc[1,o,i,g]
// A-tile [128 x 64] generated on the fly (k-local = s*32+g), B = fc_bf natural layout.
__global__ __launch_bounds__(512) void k_fourier(const float* __restrict__ agg,
                                                 const bf16_t* __restrict__ fcb,
                                                 float* __restrict__ P) {
  __shared__ float  zl[128 * 69];
  __shared__ bf16_t smA[128 * 72];
  __shared__ bf16_t smB[128 * 72];
  const int tid = threadIdx.x;
  const int bx = blockIdx.x;                  // 256 blocks
  const int q = bx & 3, nb = (bx >> 2) & 1, mb = bx >> 3;
  const int m0 = mb * 128, n0 = nb * 128, i0 = q * 64;
  const int wv = tid >> 6, lane = tid & 63;
  const int wm = wv >> 2, wn = wv & 3;
  const int lr = lane & 15, lk = (lane >> 4) * 8;

  // stage z tile [128 rows x 64 i-cols] (fp32 — precision matters: d/dz amplified by k<=32)
#pragma unroll
  for (int r = 0; r < 4; r++) {
    int task = tid + r * 512;                 // 2048 tasks: 128 x 16 float4
    int row = task >> 4, seg = task & 15;
    float4 v = *(const float4*)(agg + (size_t)(m0 + row) * 256 + i0 + seg * 4);
    zl[row * 69 + seg * 4 + 0] = v.x;
    zl[row * 69 + seg * 4 + 1] = v.y;
    zl[row * 69 + seg * 4 + 2] = v.z;
    zl[row * 69 + seg * 4 + 3] = v.w;
  }
  __syncthreads();

  f32x4 acc[4][2];
#pragma unroll
  for (int i = 0; i < 4; i++)
#pragma unroll
    for (int j = 0; j < 2; j++) acc[i][j] = f32x4{0.f, 0.f, 0.f, 0.f};

  const int zrow = tid & 127;                 // same row for both A-gen reps
  for (int ii = 0; ii < 64; ii++) {
    // B global loads (fc[s][o][i][g]: 8 g's contiguous = 16B)
    bf16x8 br[2];
#pragma unroll
    for (int r = 0; r < 2; r++) {
      int task = tid + r * 512;               // 128 o x 8 segs
      int o = task >> 3, seg = task & 7;
      int s = seg >> 2, g0 = (seg & 3) * 8;
      br[r] = *(const bf16x8*)(fcb + (size_t)s * 2097152 +
                               (size_t)(n0 + o) * 8192 + (size_t)(i0 + ii) * 32 + g0);
    }
    __syncthreads();
#pragma unroll
    for (int r = 0; r < 2; r++) {
      int task = tid + r * 512;
      int o = task >> 3, seg = task & 7;
      *(bf16x8*)(smB + o * 72 + seg * 8) = br[r];
    }
    // A-gen: hardware v_cos/v_sin take REVOLUTIONS; fract-reduce first.
    float zr = zl[zrow * 69 + ii] * 0.15915494309189535f;
    {   // rep 0: oct 0..3 -> cos
      int oct = tid >> 7;                     // 0..3
      int g0 = oct * 8;
      bf16x8 a;
#pragma unroll
      for (int j = 0; j < 8; j++) {
        float rev = zr * (float)(g0 + j + 1);
        rev -= floorf(rev);
        a[j] = (bf16_t)cos_rev(rev);
      }
      *(bf16x8*)(smA + zrow * 72 + oct * 8) = a;
    }
    {   // rep 1: oct 4..7 -> sin
      int oct = ((tid + 512) >> 7);           // 4..7
      int g0 = (oct & 3) * 8;
      bf16x8 a;
#pragma unroll
      for (int j = 0; j < 8; j++) {
        float rev = zr * (float)(g0 + j + 1);
        rev -= floorf(rev);
        a[j] = (bf16_t)sin_rev(rev);
      }
      *(bf16x8*)(smA + zrow * 72 + oct * 8) = a;
    }
    __syncthreads();
#pragma unroll
    for (int ks = 0; ks < 2; ks++) {
      bf16x8 af[4], bfr[2];
#pragma unroll
      for (int i = 0; i < 4; i++)
        af[i] = *(const bf16x8*)(smA + (wm * 64 + i * 16 + lr) * 72 + ks * 32 + lk);
#pragma unroll
      for (int j = 0; j < 2; j++)
        bfr[j] = *(const bf16x8*)(smB + (wn * 32 + j * 16 + lr) * 72 + ks * 32 + lk);
#pragma unroll
      for (int i = 0; i < 4; i++)
#pragma unroll
        for (int j = 0; j < 2; j++)
          acc[i][j] = __builtin_amdgcn_mfma_f32_16x16x32_bf16(af[i], bfr[j], acc[i][j], 0, 0, 0);
    }
  }
  float* outp = P + (size_t)q * 1048576;
#pragma unroll
  for (int i = 0; i < 4; i++)
#pragma unroll
    for (int j = 0; j < 2; j++) {
      int col = n0 + wn * 32 + j * 16 + lr;
#pragma unroll
      for (int r = 0; r < 4; r++) {
        int row = m0 + wm * 64 + i * 16 + (lane >> 4) * 4 + r;
        outp[(size_t)row * 256 + col] = acc[i][j][r];
      }
    }
}

// ---------------- reduce K-split partials + new_s epilogue ----------------
__global__ __launch_bounds__(256) void k_freduce(const float* __restrict__ P,
                                                 const float* __restrict__ fb,
                                                 const float* __restrict__ tk,
                                                 const float* __restrict__ s0,
                                                 float* __restrict__ news,
                                                 bf16_t* __restrict__ sob) {
  int stride = gridDim.x * blockDim.x;
  for (int i = blockIdx.x * blockDim.x + threadIdx.x; i < 1048576; i += stride) {
    int o = i & 255;
    float v = P[i] + P[i + 1048576] + P[i + 2097152] + P[i + 3145728] + fb[o];
    sob[i] = (bf16_t)v;
    news[i] = tk[o] * v + tk[256 + o] * s0[i];
  }
}

// ---------------- cell state: c = f*c0 + i*tanh(ccand) ----------------
__global__ __launch_bounds__(256) void k_cell(const float* __restrict__ gates,
                                              const float* __restrict__ c0,
                                              float* __restrict__ c_out,
                                              float* __restrict__ tc) {
  int stride = gridDim.x * blockDim.x;
  for (int i = blockIdx.x * blockDim.x + threadIdx.x; i < 2097152; i += stride) {
    int b = i >> 9, j = i & 511;
    const float* g = gates + (size_t)b * 1536;
    float c = g[512 + j] * c0[i] + g[j] * tanhf(g[1024 + j]);
    c_out[i] = c;
    tc[i] = tanhf(c);
  }
}

// ---------------- h = LN(o * tanh(c)) ----------------
__global__ __launch_bounds__(256) void k_ln(const float* __restrict__ o,
                                            const float* __restrict__ tc,
                                            const float* __restrict__ lg,
                                            const float* __restrict__ lb,
                                            float* __restrict__ h) {
  int b = blockIdx.x, tid = threadIdx.x;
  float2 ov = *(const float2*)(o + (size_t)b * 512 + tid * 2);
  float2 tv = *(const float2*)(tc + (size_t)b * 512 + tid * 2);
  float h0 = ov.x * tv.x, h1 = ov.y * tv.y;
  float s = h0 + h1, ss = h0 * h0 + h1 * h1;
#pragma unroll
  for (int off = 32; off; off >>= 1) {
    s += __shfl_xor(s, off);
    ss += __shfl_xor(ss, off);
  }
  __shared__ float red[8];
  int wid = tid >> 6;
  if ((tid & 63) == 0) { red[wid] = s; red[4 + wid] = ss; }
  __syncthreads();
  s = red[0] + red[1] + red[2] + red[3];
  ss = red[4] + red[5] + red[6] + red[7];
  float mu = s * (1.f / 512.f);
  float var = ss * (1.f / 512.f) - mu * mu;
  float rs = rsqrtf(var + 1e-5f);
  int j = tid * 2;
  h[(size_t)b * 512 + j]     = (h0 - mu) * rs * lg[j]     + lb[j];
  h[(size_t)b * 512 + j + 1] = (h1 - mu) * rs * lg[j + 1] + lb[j + 1];
}

// ---------------- launcher ----------------
extern "C" void kernel_launch(void* const* d_in, const int* in_sizes, int n_in,
                              void* d_out, int out_size, void* d_ws, size_t ws_size,
                              hipStream_t stream) {
  const float* x    = (const float*)d_in[0];
  const float* h0   = (const float*)d_in[1];
  const float* c0   = (const float*)d_in[2];
  const float* s0   = (const float*)d_in[3];
  const float* Wk   = (const float*)d_in[4];
  const float* Wr   = (const float*)d_in[5];
  const float* bias = (const float*)d_in[6];
  const float* kx   = (const float*)d_in[7];
  const float* kh   = (const float*)d_in[8];
  const float* tk   = (const float*)d_in[9];
  const float* fc   = (const float*)d_in[10];
  const float* fb   = (const float*)d_in[11];
  const float* aw   = (const float*)d_in[12];
  const float* ab   = (const float*)d_in[13];
  const float* lg   = (const float*)d_in[14];
  const float* lbp  = (const float*)d_in[15];
  float* out = (float*)d_out;
  char* ws = (char*)d_ws;
  auto BF = [&](unsigned long long off) { return (bf16_t*)(ws + off); };
  auto FP = [&](unsigned long long off) { return (float*)(ws + off); };

  // --- conversions ---
  k_conv<true ><<<1024, 256, 0, stream>>>(x,  BF(O_XHI), BF(O_XLO), NB * IN_DIM);
  k_conv<false><<<1024, 256, 0, stream>>>(h0, BF(O_H0),  nullptr,   NB * HID);
  k_conv<true ><<<1024, 256, 0, stream>>>(s0, BF(O_S0H), BF(O_S0L), NB * SUB);
  k_conv<false><<<2048, 256, 0, stream>>>(fc, BF(O_FCB), nullptr,   2 * SUB * SUB * GRID_);
  k_tconv<false><<<dim3(48, 8),  256, 0, stream>>>(Wk, BF(O_KT),  nullptr,   256, 1536);
  k_tconv<false><<<dim3(48, 16), 256, 0, stream>>>(Wr, BF(O_RKT), nullptr,   512, 1536);
  k_tconv<false><<<dim3(16, 8),  256, 0, stream>>>(aw, BF(O_AWT), nullptr,   256, 512);
  k_tconv<true ><<<dim3(8, 8),   256, 0, stream>>>(kx, BF(O_KXH), BF(O_KXL), 256, 256);
  k_tconv<true ><<<dim3(8, 8),   256, 0, stream>>>(kh, BF(O_KHH), BF(O_KHL), 256, 256);

  // --- gates GEMM: sigmoid(x@Wk + h0@Wr + bias) -> gates [4096][1536] ---
  {
    GArgs g{};
    g.p[0] = { BF(O_XHI), BF(O_KT),  256, 256, 256 };
    g.p[1] = { BF(O_H0),  BF(O_RKT), 512, 512, 512 };
    g.np = 2; g.N = 1536; g.bias = bias; g.act = 1;
    g.out = FP(O_GATES); g.ldout = 1536;
    k_gemm<<<dim3(12, 32), 512, 0, stream>>>(g);
  }
  // --- cell: c = f*c0 + i*tanh(cc) -> d_out[2M..4M), tanh(c) -> ws ---
  k_cell<<<2048, 256, 0, stream>>>(FP(O_GATES), c0, out + 2097152, FP(O_TC));

  // --- agg GEMM (fp32-accurate via hi/lo split): agg = x@kx + s0@kh ---
  // (GATES is dead now; AGG/P overlay its region)
  {
    GArgs g{};
    g.p[0] = { BF(O_XHI), BF(O_KXH), 256, 256, 256 };
    g.p[1] = { BF(O_XHI), BF(O_KXL), 256, 256, 256 };
    g.p[2] = { BF(O_XLO), BF(O_KXH), 256, 256, 256 };
    g.p[3] = { BF(O_S0H), BF(O_KHH), 256, 256, 256 };
    g.p[4] = { BF(O_S0H), BF(O_KHL), 256, 256, 256 };
    g.p[5] = { BF(O_S0L), BF(O_KHH), 256, 256, 256 };
    g.np = 6; g.N = 256; g.bias = nullptr; g.act = 0;
    g.out = FP(O_AGG); g.ldout = 256;
    k_gemm<<<dim3(2, 32), 512, 0, stream>>>(g);
  }
  // --- Fourier KAN (K-split x4) ---
  k_fourier<<<256, 512, 0, stream>>>(FP(O_AGG), BF(O_FCB), FP(O_P));
  // --- reduce partials, emit new_s (d_out[4M..5M)) + sub_out bf16 ---
  k_freduce<<<2048, 256, 0, stream>>>(FP(O_P), fb, tk, s0, out + 4194304, BF(O_SOB));

  // --- out-proj GEMM: o = sigmoid(sub_out@agg_w + agg_b) ---
  // (FCB is dead now; O overlays it)
  {
    GArgs g{};
    g.p[0] = { BF(O_SOB), BF(O_AWT), 256, 256, 256 };
    g.np = 1; g.N = 512; g.bias = ab; g.act = 1;
    g.out = FP(O_O); g.ldout = 512;
    k_gemm<<<dim3(4, 32), 512, 0, stream>>>(g);
  }
  // --- h = LN(o * tanh(c)) -> d_out[0..2M) ---
  k_ln<<<4096, 256, 0, stream>>>(FP(O_O), FP(O_TC), lg, lbp, out);
}

// Round 3
// 138.218 us; speedup vs baseline: 1.2804x; 1.2804x over previous
//
#include <hip/hip_runtime.h>
#include <hip/hip_bf16.h>

typedef __bf16 bf16_t;
typedef __bf16 bf16x4 __attribute__((ext_vector_type(4)));
typedef __bf16 bf16x8 __attribute__((ext_vector_type(8)));
typedef float  f32x4  __attribute__((ext_vector_type(4)));

// ---------------- problem constants ----------------
#define NB 4096
#define IN_DIM 256
#define HID 512
#define SUB 256
#define GRID_ 32

// ---------------- trig helpers (input: revolutions, pre-reduced) ----
__device__ __forceinline__ float cos_rev(float rev) {
#if __has_builtin(__builtin_amdgcn_cosf)
  return __builtin_amdgcn_cosf(rev);
#else
  return __cosf(rev * 6.283185307179586f);
#endif
}
__device__ __forceinline__ float sin_rev(float rev) {
#if __has_builtin(__builtin_amdgcn_sinf)
  return __builtin_amdgcn_sinf(rev);
#else
  return __sinf(rev * 6.283185307179586f);
#endif
}
__device__ __forceinline__ float sigm(float v) { return 1.f / (1.f + __expf(-v)); }

// ---------------- workspace layout (bytes), max used ~53 MB ----------------
// O overlays FCB (fcb dead after k_fourier; outproj writes O after freduce).
#define O_XHI   0ull
#define O_XLO   2097152ull
#define O_H0    4194304ull
#define O_S0H   8388608ull
#define O_S0L   10485760ull
#define O_FCB   12582912ull
#define O_O     12582912ull
#define O_KT    20971520ull
#define O_RKT   21757952ull
#define O_AWT   23330816ull
#define O_KXH   23592960ull
#define O_KXL   23724032ull
#define O_KHH   23855104ull
#define O_KHL   23986176ull
#define O_TC    24117248ull
#define O_SOB   32505856ull
#define O_AGG   34603008ull
#define O_P     38797312ull
// P end = 55574528

// ---------------- fused plain conversions (float4) ----------------
// x (LO), h0, s0 (LO), fc  -> bf16 buffers. Quad counts: 262144 / 524288 / 262144 / 1048576.
__global__ __launch_bounds__(256) void k_prep(const float* __restrict__ x,
                                              const float* __restrict__ h0,
                                              const float* __restrict__ s0,
                                              const float* __restrict__ fc,
                                              bf16_t* __restrict__ xhi, bf16_t* __restrict__ xlo,
                                              bf16_t* __restrict__ h0b,
                                              bf16_t* __restrict__ s0h, bf16_t* __restrict__ s0l,
                                              bf16_t* __restrict__ fcb) {
  int stride = gridDim.x * blockDim.x;
  for (int q = blockIdx.x * blockDim.x + threadIdx.x; q < 2097152; q += stride) {
    const float* src; bf16_t* hi; bf16_t* lo = nullptr; int base;
    if (q < 262144)       { src = x;  hi = xhi; lo = xlo; base = q; }
    else if (q < 786432)  { src = h0; hi = h0b;           base = q - 262144; }
    else if (q < 1048576) { src = s0; hi = s0h; lo = s0l; base = q - 786432; }
    else                  { src = fc; hi = fcb;           base = q - 1048576; }
    float4 v = *(const float4*)(src + (size_t)base * 4);
    bf16x4 h; h[0] = (bf16_t)v.x; h[1] = (bf16_t)v.y; h[2] = (bf16_t)v.z; h[3] = (bf16_t)v.w;
    *(bf16x4*)(hi + (size_t)base * 4) = h;
    if (lo) {
      bf16x4 l;
      l[0] = (bf16_t)(v.x - (float)h[0]); l[1] = (bf16_t)(v.y - (float)h[1]);
      l[2] = (bf16_t)(v.z - (float)h[2]); l[3] = (bf16_t)(v.w - (float)h[3]);
      *(bf16x4*)(lo + (size_t)base * 4) = l;
    }
  }
}

// ---------------- transpose-convert body: f32 [R][C] -> bf16 [C][R] ----------
__device__ __forceinline__ void tconv_body(const float* __restrict__ src,
                                           bf16_t* __restrict__ hi,
                                           bf16_t* __restrict__ lo,
                                           int R, int C, int bx, int by, bool wantlo) {
  __shared__ float t[32][33];
  int c0 = bx * 32, r0 = by * 32;
  int tx = threadIdx.x & 31, ty = threadIdx.x >> 5;  // 32 x 8
#pragma unroll
  for (int rr = 0; rr < 4; rr++) {
    int r = ty + rr * 8;
    t[r][tx] = src[(size_t)(r0 + r) * C + c0 + tx];
  }
  __syncthreads();
#pragma unroll
  for (int rr = 0; rr < 4; rr++) {
    int cl = ty + rr * 8;
    float f = t[tx][cl];
    bf16_t h = (bf16_t)f;
    size_t oi = (size_t)(c0 + cl) * R + r0 + tx;
    hi[oi] = h;
    if (wantlo) lo[oi] = (bf16_t)(f - (float)h);
  }
}

// 3 no-residual transposes in one launch: Wk(384 blk), Wr(768), aw(128)
__global__ __launch_bounds__(256) void k_tconv3(const float* __restrict__ Wk,
                                                const float* __restrict__ Wr,
                                                const float* __restrict__ aw,
                                                bf16_t* __restrict__ kt,
                                                bf16_t* __restrict__ rkt,
                                                bf16_t* __restrict__ awt) {
  int b = blockIdx.x;
  const float* src; bf16_t* hi; int R, C, bx, by;
  if (b < 384)       { src = Wk; hi = kt;  R = 256; C = 1536; bx = b % 48; by = b / 48; }
  else if (b < 1152) { b -= 384;  src = Wr; hi = rkt; R = 512; C = 1536; bx = b % 48; by = b / 48; }
  else               { b -= 1152; src = aw; hi = awt; R = 256; C = 512;  bx = b % 16; by = b / 16; }
  tconv_body(src, hi, nullptr, R, C, bx, by, false);
}

// 2 residual transposes: kx(64 blk), kh(64)
__global__ __launch_bounds__(256) void k_tconv2(const float* __restrict__ kx,
                                                const float* __restrict__ kh,
                                                bf16_t* __restrict__ kxh, bf16_t* __restrict__ kxl,
                                                bf16_t* __restrict__ khh, bf16_t* __restrict__ khl) {
  int b = blockIdx.x;
  const float* src; bf16_t *hi, *lo; int bx, by;
  if (b < 64) { src = kx; hi = kxh; lo = kxl; bx = b % 8; by = b / 8; }
  else        { b -= 64; src = kh; hi = khh; lo = khl; bx = b % 8; by = b / 8; }
  tconv_body(src, hi, lo, 256, 256, bx, by, true);
}

// ---------------- generic multi-pass bf16 MFMA GEMM (templated tile) --------
struct Pass { const bf16_t* A; const bf16_t* Bt; int K; int lda; int ldbt; };
struct GArgs {
  Pass p[6]; int np;
  const float* bias;        // may be null
  int act;                  // 1 -> sigmoid(acc+bias)
  float* out; int ldout;
};

template<int BM, int BN>
__global__ __launch_bounds__(512) void k_gemm(GArgs g) {
  constexpr int MI = BM / 32;          // m-frags per wave (wave m-size BM/2)
  constexpr int NJ = BN / 64;          // n-frags per wave (wave n-size BN/4)
  constexpr int IA = (BM * 8) / 512;
  constexpr int IB = (BN * 8) / 512;
  __shared__ bf16_t smA[BM * 72];
  __shared__ bf16_t smB[BN * 72];
  const int tid = threadIdx.x;
  const int m0 = blockIdx.y * BM, n0 = blockIdx.x * BN;
  const int wv = tid >> 6, lane = tid & 63;
  const int wm = wv >> 2, wn = wv & 3;
  const int lr = lane & 15, lk = (lane >> 4) * 8;

  f32x4 acc[MI][NJ];
#pragma unroll
  for (int i = 0; i < MI; i++)
#pragma unroll
    for (int j = 0; j < NJ; j++) acc[i][j] = f32x4{0.f, 0.f, 0.f, 0.f};

  for (int ps = 0; ps < g.np; ps++) {
    const bf16_t* A = g.p[ps].A;
    const bf16_t* Bt = g.p[ps].Bt;
    const int K = g.p[ps].K, lda = g.p[ps].lda, ldbt = g.p[ps].ldbt;
    for (int k0 = 0; k0 < K; k0 += 64) {
      bf16x8 ar[IA], br[IB];
#pragma unroll
      for (int r = 0; r < IA; r++) {
        int task = tid + r * 512, row = task >> 3, seg = task & 7;
        ar[r] = *(const bf16x8*)(A + (size_t)(m0 + row) * lda + k0 + seg * 8);
      }
#pragma unroll
      for (int r = 0; r < IB; r++) {
        int task = tid + r * 512, row = task >> 3, seg = task & 7;
        br[r] = *(const bf16x8*)(Bt + (size_t)(n0 + row) * ldbt + k0 + seg * 8);
      }
      __syncthreads();
#pragma unroll
      for (int r = 0; r < IA; r++) {
        int task = tid + r * 512, row = task >> 3, seg = task & 7;
        *(bf16x8*)(smA + row * 72 + seg * 8) = ar[r];
      }
#pragma unroll
      for (int r = 0; r < IB; r++) {
        int task = tid + r * 512, row = task >> 3, seg = task & 7;
        *(bf16x8*)(smB + row * 72 + seg * 8) = br[r];
      }
      __syncthreads();
#pragma unroll
      for (int ks = 0; ks < 2; ks++) {
        bf16x8 af[MI], bfr[NJ];
#pragma unroll
        for (int i = 0; i < MI; i++)
          af[i] = *(const bf16x8*)(smA + (wm * (BM / 2) + i * 16 + lr) * 72 + ks * 32 + lk);
#pragma unroll
        for (int j = 0; j < NJ; j++)
          bfr[j] = *(const bf16x8*)(smB + (wn * (BN / 4) + j * 16 + lr) * 72 + ks * 32 + lk);
#pragma unroll
        for (int i = 0; i < MI; i++)
#pragma unroll
          for (int j = 0; j < NJ; j++)
            acc[i][j] = __builtin_amdgcn_mfma_f32_16x16x32_bf16(af[i], bfr[j], acc[i][j], 0, 0, 0);
      }
    }
  }
#pragma unroll
  for (int i = 0; i < MI; i++)
#pragma unroll
    for (int j = 0; j < NJ; j++) {
      int col = n0 + wn * (BN / 4) + j * 16 + lr;
      float bb = g.bias ? g.bias[col] : 0.f;
#pragma unroll
      for (int r = 0; r < 4; r++) {
        int row = m0 + wm * (BM / 2) + i * 16 + (lane >> 4) * 4 + r;
        float v = acc[i][j][r] + bb;
        if (g.act == 1) v = sigm(v);
        g.out[(size_t)row * g.ldout + col] = v;
      }
    }
}

// ---------------- fused gates GEMM + cell state ----------------
// Per block: 64 rows x 128 cols x {i,f,c} gate tiles; epilogue computes
// c = sigm(f)*c0 + sigm(i)*tanh(sigm(cc)), tc = tanh(c). gates never hit HBM.
struct GatesArgs {
  const bf16_t* xhi; const bf16_t* h0b; const bf16_t* kt; const bf16_t* rkt;
  const float* bias; const float* c0; float* c_out; float* tc;
};

__global__ __launch_bounds__(512, 2) void k_gates(GatesArgs ga) {
  __shared__ bf16_t smA[64 * 72];
  __shared__ bf16_t smB[3 * 128 * 72];
  const int tid = threadIdx.x;
  const int n0 = blockIdx.x * 128;       // within 512
  const int m0 = blockIdx.y * 64;
  const int wv = tid >> 6, lane = tid & 63;
  const int wm = wv >> 2, wn = wv & 3;
  const int lr = lane & 15, lk = (lane >> 4) * 8;

  f32x4 acc[3][2][2];
#pragma unroll
  for (int t = 0; t < 3; t++)
#pragma unroll
    for (int i = 0; i < 2; i++)
#pragma unroll
      for (int j = 0; j < 2; j++) acc[t][i][j] = f32x4{0.f, 0.f, 0.f, 0.f};

  for (int ps = 0; ps < 2; ps++) {
    const bf16_t* A  = ps ? ga.h0b : ga.xhi;
    const bf16_t* Bt = ps ? ga.rkt : ga.kt;
    const int K = ps ? 512 : 256, ld = K;
    for (int k0 = 0; k0 < K; k0 += 64) {
      int arow = tid >> 3, aseg = tid & 7;
      bf16x8 ar = *(const bf16x8*)(A + (size_t)(m0 + arow) * ld + k0 + aseg * 8);
      bf16x8 br[6];
#pragma unroll
      for (int r = 0; r < 6; r++) {
        int task = tid + r * 512;
        int gate = task >> 10, rem = task & 1023, o = rem >> 3, seg = rem & 7;
        br[r] = *(const bf16x8*)(Bt + (size_t)(gate * 512 + n0 + o) * ld + k0 + seg * 8);
      }
      __syncthreads();
      *(bf16x8*)(smA + arow * 72 + aseg * 8) = ar;
#pragma unroll
      for (int r = 0; r < 6; r++) {
        int task = tid + r * 512;
        int gate = task >> 10, rem = task & 1023, o = rem >> 3, seg = rem & 7;
        *(bf16x8*)(smB + (gate * 128 + o) * 72 + seg * 8) = br[r];
      }
      __syncthreads();
#pragma unroll
      for (int ks = 0; ks < 2; ks++) {
        bf16x8 af[2];
#pragma unroll
        for (int i = 0; i < 2; i++)
          af[i] = *(const bf16x8*)(smA + (wm * 32 + i * 16 + lr) * 72 + ks * 32 + lk);
#pragma unroll
        for (int t = 0; t < 3; t++) {
          bf16x8 bfr[2];
#pragma unroll
          for (int j = 0; j < 2; j++)
            bfr[j] = *(const bf16x8*)(smB + (t * 128 + wn * 32 + j * 16 + lr) * 72 + ks * 32 + lk);
#pragma unroll
          for (int i = 0; i < 2; i++)
#pragma unroll
            for (int j = 0; j < 2; j++)
              acc[t][i][j] = __builtin_amdgcn_mfma_f32_16x16x32_bf16(af[i], bfr[j], acc[t][i][j], 0, 0, 0);
        }
      }
    }
  }
  // epilogue: cell state
#pragma unroll
  for (int i = 0; i < 2; i++)
#pragma unroll
    for (int j = 0; j < 2; j++) {
      int col = n0 + wn * 32 + j * 16 + lr;            // 0..511
      float bi = ga.bias[col], bf_ = ga.bias[512 + col], bc = ga.bias[1024 + col];
#pragma unroll
      for (int r = 0; r < 4; r++) {
        int row = m0 + wm * 32 + i * 16 + (lane >> 4) * 4 + r;
        size_t idx = (size_t)row * 512 + col;
        float iv = sigm(acc[0][i][j][r] + bi);
        float fv = sigm(acc[1][i][j][r] + bf_);
        float cc = sigm(acc[2][i][j][r] + bc);
        float cv = fv * ga.c0[idx] + iv * tanhf(cc);
        ga.c_out[idx] = cv;
        ga.tc[idx] = tanhf(cv);
      }
    }
}

// ---------------- Fourier-KAN GEMM v2 ----------------
// BM=64, BN=128, i-chunk 64 (q=4). grid 512 = 2 blocks/CU.
// Double-buffered LDS, ONE barrier per K-step; B prefetched one iter ahead;
// per-thread trig: one rev per cos/sin pair (8 trig / thread / iter).
__global__ __launch_bounds__(512, 4) void k_fourier(const float* __restrict__ agg,
                                                    const bf16_t* __restrict__ fcb,
                                                    float* __restrict__ P) {
  __shared__ float  zl[64 * 69];
  __shared__ bf16_t Asm[2][64 * 72];
  __shared__ bf16_t Bsm[2][128 * 72];
  const int tid = threadIdx.x;
  const int bx = blockIdx.x;                  // 512 blocks
  const int q = bx & 3, nb = (bx >> 2) & 1, mb = bx >> 3;
  const int m0 = mb * 64, n0 = nb * 128, i0 = q * 64;
  const int wv = tid >> 6, lane = tid & 63;
  const int wm = wv >> 2, wn = wv & 3;
  const int lr = lane & 15, lk = (lane >> 4) * 8;
  const int arow = tid >> 3;                  // 0..63 (A-gen row)
  const int hq = tid & 7;                     // g-quad

  // stage z tile [64 rows x 64 i] fp32
#pragma unroll
  for (int r = 0; r < 2; r++) {
    int task = tid + r * 512, row = task >> 4, seg = task & 15;
    float4 v = *(const float4*)(agg + (size_t)(m0 + row) * 256 + i0 + seg * 4);
    zl[row * 69 + seg * 4 + 0] = v.x;
    zl[row * 69 + seg * 4 + 1] = v.y;
    zl[row * 69 + seg * 4 + 2] = v.z;
    zl[row * 69 + seg * 4 + 3] = v.w;
  }
  __syncthreads();

  // helpers as lambdas
  auto genA = [&](int ii, bf16_t* Ab) {
    float zr = zl[arow * 69 + ii] * 0.15915494309189535f;
    bf16x4 cv, sv;
#pragma unroll
    for (int t = 0; t < 4; t++) {
      float rev = zr * (float)(hq * 4 + t + 1);
      rev -= floorf(rev);
      cv[t] = (bf16_t)cos_rev(rev);
      sv[t] = (bf16_t)sin_rev(rev);
    }
    *(bf16x4*)(Ab + arow * 72 + hq * 4) = cv;
    *(bf16x4*)(Ab + arow * 72 + 32 + hq * 4) = sv;
  };
  auto loadB = [&](int ii, bf16x8* br) {
#pragma unroll
    for (int r = 0; r < 2; r++) {
      int task = tid + r * 512, o = task >> 3, seg = task & 7;
      int s = seg >> 2, g0 = (seg & 3) * 8;
      br[r] = *(const bf16x8*)(fcb + (size_t)s * 2097152 +
                               (size_t)(n0 + o) * 8192 + (size_t)(i0 + ii) * 32 + g0);
    }
  };
  auto writeB = [&](const bf16x8* br, bf16_t* Bb) {
#pragma unroll
    for (int r = 0; r < 2; r++) {
      int task = tid + r * 512, o = task >> 3, seg = task & 7;
      *(bf16x8*)(Bb + o * 72 + seg * 8) = br[r];
    }
  };

  f32x4 acc[2][2];
#pragma unroll
  for (int i = 0; i < 2; i++)
#pragma unroll
    for (int j = 0; j < 2; j++) acc[i][j] = f32x4{0.f, 0.f, 0.f, 0.f};

  // prologue: fill buffer 0
  {
    bf16x8 br[2];
    loadB(0, br);
    genA(0, Asm[0]);
    writeB(br, Bsm[0]);
  }
  __syncthreads();

  for (int ii = 0; ii < 64; ii++) {
    const int cur = ii & 1, nxt = cur ^ 1;
    // issue all fragment reads first
    bf16x8 af[2][2], bfr[2][2];
#pragma unroll
    for (int ks = 0; ks < 2; ks++) {
#pragma unroll
      for (int i = 0; i < 2; i++)
        af[ks][i] = *(const bf16x8*)(Asm[cur] + (wm * 32 + i * 16 + lr) * 72 + ks * 32 + lk);
#pragma unroll
      for (int j = 0; j < 2; j++)
        bfr[ks][j] = *(const bf16x8*)(Bsm[cur] + (wn * 32 + j * 16 + lr) * 72 + ks * 32 + lk);
    }
    if (ii < 63) {
      bf16x8 br[2];
      loadB(ii + 1, br);                 // global, in flight under trig+MFMA
      genA(ii + 1, Asm[nxt]);            // VALU overlaps frag-read latency
      writeB(br, Bsm[nxt]);
    }
#pragma unroll
    for (int ks = 0; ks < 2; ks++)
#pragma unroll
      for (int i = 0; i < 2; i++)
#pragma unroll
        for (int j = 0; j < 2; j++)
          acc[i][j] = __builtin_amdgcn_mfma_f32_16x16x32_bf16(af[ks][i], bfr[ks][j], acc[i][j], 0, 0, 0);
    __syncthreads();
  }

  float* outp = P + (size_t)q * 1048576;
#pragma unroll
  for (int i = 0; i < 2; i++)
#pragma unroll
    for (int j = 0; j < 2; j++) {
      int col = n0 + wn * 32 + j * 16 + lr;
#pragma unroll
      for (int r = 0; r < 4; r++) {
        int row = m0 + wm * 32 + i * 16 + (lane >> 4) * 4 + r;
        outp[(size_t)row * 256 + col] = acc[i][j][r];
      }
    }
}

// ---------------- reduce K-split partials + new_s epilogue (float4) ---------
__global__ __launch_bounds__(256) void k_freduce(const float* __restrict__ P,
                                                 const float* __restrict__ fb,
                                                 const float* __restrict__ tk,
                                                 const float* __restrict__ s0,
                                                 float* __restrict__ news,
                                                 bf16_t* __restrict__ sob) {
  int stride = gridDim.x * blockDim.x;
  const float4* P4 = (const float4*)P;
  for (int qd = blockIdx.x * blockDim.x + threadIdx.x; qd < 262144; qd += stride) {
    int i = qd * 4, o = i & 255;
    float4 a = P4[qd], b = P4[qd + 262144], c = P4[qd + 524288], d = P4[qd + 786432];
    float4 s = *(const float4*)(s0 + i);
    float v0 = a.x + b.x + c.x + d.x + fb[o + 0];
    float v1 = a.y + b.y + c.y + d.y + fb[o + 1];
    float v2 = a.z + b.z + c.z + d.z + fb[o + 2];
    float v3 = a.w + b.w + c.w + d.w + fb[o + 3];
    bf16x4 sb; sb[0] = (bf16_t)v0; sb[1] = (bf16_t)v1; sb[2] = (bf16_t)v2; sb[3] = (bf16_t)v3;
    *(bf16x4*)(sob + i) = sb;
    float4 ns;
    ns.x = tk[o + 0] * v0 + tk[256 + o + 0] * s.x;
    ns.y = tk[o + 1] * v1 + tk[256 + o + 1] * s.y;
    ns.z = tk[o + 2] * v2 + tk[256 + o + 2] * s.z;
    ns.w = tk[o + 3] * v3 + tk[256 + o + 3] * s.w;
    *(float4*)(news + i) = ns;
  }
}

// ---------------- h = LN(o * tanh(c)) ----------------
__global__ __launch_bounds__(256) void k_ln(const float* __restrict__ o,
                                            const float* __restrict__ tc,
                                            const float* __restrict__ lg,
                                            const float* __restrict__ lb,
                                            float* __restrict__ h) {
  int b = blockIdx.x, tid = threadIdx.x;
  float2 ov = *(const float2*)(o + (size_t)b * 512 + tid * 2);
  float2 tv = *(const float2*)(tc + (size_t)b * 512 + tid * 2);
  float h0 = ov.x * tv.x, h1 = ov.y * tv.y;
  float s = h0 + h1, ss = h0 * h0 + h1 * h1;
#pragma unroll
  for (int off = 32; off; off >>= 1) {
    s += __shfl_xor(s, off);
    ss += __shfl_xor(ss, off);
  }
  __shared__ float red[8];
  int wid = tid >> 6;
  if ((tid & 63) == 0) { red[wid] = s; red[4 + wid] = ss; }
  __syncthreads();
  s = red[0] + red[1] + red[2] + red[3];
  ss = red[4] + red[5] + red[6] + red[7];
  float mu = s * (1.f / 512.f);
  float var = ss * (1.f / 512.f) - mu * mu;
  float rs = rsqrtf(var + 1e-5f);
  int j = tid * 2;
  h[(size_t)b * 512 + j]     = (h0 - mu) * rs * lg[j]     + lb[j];
  h[(size_t)b * 512 + j + 1] = (h1 - mu) * rs * lg[j + 1] + lb[j + 1];
}

// ---------------- launcher ----------------
extern "C" void kernel_launch(void* const* d_in, const int* in_sizes, int n_in,
                              void* d_out, int out_size, void* d_ws, size_t ws_size,
                              hipStream_t stream) {
  const float* x    = (const float*)d_in[0];
  const float* h0   = (const float*)d_in[1];
  const float* c0   = (const float*)d_in[2];
  const float* s0   = (const float*)d_in[3];
  const float* Wk   = (const float*)d_in[4];
  const float* Wr   = (const float*)d_in[5];
  const float* bias = (const float*)d_in[6];
  const float* kx   = (const float*)d_in[7];
  const float* kh   = (const float*)d_in[8];
  const float* tk   = (const float*)d_in[9];
  const float* fc   = (const float*)d_in[10];
  const float* fb   = (const float*)d_in[11];
  const float* aw   = (const float*)d_in[12];
  const float* ab   = (const float*)d_in[13];
  const float* lg   = (const float*)d_in[14];
  const float* lbp  = (const float*)d_in[15];
  float* out = (float*)d_out;
  char* ws = (char*)d_ws;
  auto BF = [&](unsigned long long off) { return (bf16_t*)(ws + off); };
  auto FP = [&](unsigned long long off) { return (float*)(ws + off); };

  // --- conversions (3 launches) ---
  k_prep<<<2048, 256, 0, stream>>>(x, h0, s0, fc, BF(O_XHI), BF(O_XLO), BF(O_H0),
                                   BF(O_S0H), BF(O_S0L), BF(O_FCB));
  k_tconv3<<<1280, 256, 0, stream>>>(Wk, Wr, aw, BF(O_KT), BF(O_RKT), BF(O_AWT));
  k_tconv2<<<128, 256, 0, stream>>>(kx, kh, BF(O_KXH), BF(O_KXL), BF(O_KHH), BF(O_KHL));

  // --- fused gates GEMM + cell: c -> d_out[2M..4M), tanh(c) -> TC ---
  {
    GatesArgs ga{ BF(O_XHI), BF(O_H0), BF(O_KT), BF(O_RKT), bias, c0,
                  out + 2097152, FP(O_TC) };
    k_gates<<<dim3(4, 64), 512, 0, stream>>>(ga);
  }

  // --- agg GEMM (hi/lo split): agg = x@kx + s0@kh ---
  {
    GArgs g{};
    g.p[0] = { BF(O_XHI), BF(O_KXH), 256, 256, 256 };
    g.p[1] = { BF(O_XHI), BF(O_KXL), 256, 256, 256 };
    g.p[2] = { BF(O_XLO), BF(O_KXH), 256, 256, 256 };
    g.p[3] = { BF(O_S0H), BF(O_KHH), 256, 256, 256 };
    g.p[4] = { BF(O_S0H), BF(O_KHL), 256, 256, 256 };
    g.p[5] = { BF(O_S0L), BF(O_KHH), 256, 256, 256 };
    g.np = 6; g.bias = nullptr; g.act = 0;
    g.out = FP(O_AGG); g.ldout = 256;
    k_gemm<64, 64><<<dim3(4, 64), 512, 0, stream>>>(g);
  }
  // --- Fourier KAN (K-split x4, 512 blocks) ---
  k_fourier<<<512, 512, 0, stream>>>(FP(O_AGG), BF(O_FCB), FP(O_P));
  // --- reduce partials, emit new_s (d_out[4M..5M)) + sub_out bf16 ---
  k_freduce<<<1024, 256, 0, stream>>>(FP(O_P), fb, tk, s0, out + 4194304, BF(O_SOB));

  // --- out-proj GEMM: o = sigmoid(sub_out@agg_w + agg_b)  (O overlays FCB) ---
  {
    GArgs g{};
    g.p[0] = { BF(O_SOB), BF(O_AWT), 256, 256, 256 };
    g.np = 1; g.bias = ab; g.act = 1;
    g.out = FP(O_O); g.ldout = 512;
    k_gemm<64, 128><<<dim3(4, 64), 512, 0, stream>>>(g);
  }
  // --- h = LN(o * tanh(c)) -> d_out[0..2M) ---
  k_ln<<<4096, 256, 0, stream>>>(FP(O_O), FP(O_TC), lg, lbp, out);
}

// Round 4
// 129.592 us; speedup vs baseline: 1.3656x; 1.0666x over previous
//
#include <hip/hip_runtime.h>
#include <hip/hip_bf16.h>

typedef __bf16 bf16_t;
typedef __bf16 bf16x4 __attribute__((ext_vector_type(4)));
typedef __bf16 bf16x8 __attribute__((ext_vector_type(8)));
typedef float  f32x4  __attribute__((ext_vector_type(4)));

#define NB 4096
#define IN_DIM 256
#define HID 512
#define SUB 256
#define GRID_ 32

#if __has_builtin(__builtin_amdgcn_global_load_lds)
#define HAVE_GLDS 1
#else
#define HAVE_GLDS 0
#endif

// ---------------- math helpers ----------------
__device__ __forceinline__ float fractf(float x) {
#if __has_builtin(__builtin_amdgcn_fractf)
  return __builtin_amdgcn_fractf(x);
#else
  return x - floorf(x);
#endif
}
__device__ __forceinline__ float cos_rev(float rev) {   // input: revolutions in [0,1)
#if __has_builtin(__builtin_amdgcn_cosf)
  return __builtin_amdgcn_cosf(rev);
#else
  return __cosf(rev * 6.283185307179586f);
#endif
}
__device__ __forceinline__ float sin_rev(float rev) {
#if __has_builtin(__builtin_amdgcn_sinf)
  return __builtin_amdgcn_sinf(rev);
#else
  return __sinf(rev * 6.283185307179586f);
#endif
}
__device__ __forceinline__ float sigm(float v) { return 1.f / (1.f + __expf(-v)); }
// |x| <= ~40 (true here: |c| <= ~6); avoids libm tanhf branches
__device__ __forceinline__ float fast_tanh(float x) {
  float e = __expf(2.f * x);
  return (e - 1.f) / (e + 1.f);
}
#define INV2PI 0.15915494309189535f

// ---------------- workspace layout (bytes), max used ~53 MB ----------------
#define O_XHI   0ull
#define O_XLO   2097152ull
#define O_H0    4194304ull
#define O_S0H   8388608ull
#define O_S0L   10485760ull
#define O_FCB   12582912ull
#define O_O     12582912ull     // overlays FCB (fcb dead after k_fourier)
#define O_KT    20971520ull
#define O_RKT   21757952ull
#define O_AWT   23330816ull
#define O_KXH   23592960ull
#define O_KXL   23724032ull
#define O_KHH   23855104ull
#define O_KHL   23986176ull
#define O_TC    24117248ull
#define O_SOB   32505856ull
#define O_AGG   34603008ull
#define O_P     38797312ull

// ---------------- fused plain conversions (float4) ----------------
__global__ __launch_bounds__(256) void k_prep(const float* __restrict__ x,
                                              const float* __restrict__ h0,
                                              const float* __restrict__ s0,
                                              const float* __restrict__ fc,
                                              bf16_t* __restrict__ xhi, bf16_t* __restrict__ xlo,
                                              bf16_t* __restrict__ h0b,
                                              bf16_t* __restrict__ s0h, bf16_t* __restrict__ s0l,
                                              bf16_t* __restrict__ fcb) {
  int stride = gridDim.x * blockDim.x;
  for (int q = blockIdx.x * blockDim.x + threadIdx.x; q < 2097152; q += stride) {
    const float* src; bf16_t* hi; bf16_t* lo = nullptr; int base;
    if (q < 262144)       { src = x;  hi = xhi; lo = xlo; base = q; }
    else if (q < 786432)  { src = h0; hi = h0b;           base = q - 262144; }
    else if (q < 1048576) { src = s0; hi = s0h; lo = s0l; base = q - 786432; }
    else                  { src = fc; hi = fcb;           base = q - 1048576; }
    float4 v = *(const float4*)(src + (size_t)base * 4);
    bf16x4 h; h[0] = (bf16_t)v.x; h[1] = (bf16_t)v.y; h[2] = (bf16_t)v.z; h[3] = (bf16_t)v.w;
    *(bf16x4*)(hi + (size_t)base * 4) = h;
    if (lo) {
      bf16x4 l;
      l[0] = (bf16_t)(v.x - (float)h[0]); l[1] = (bf16_t)(v.y - (float)h[1]);
      l[2] = (bf16_t)(v.z - (float)h[2]); l[3] = (bf16_t)(v.w - (float)h[3]);
      *(bf16x4*)(lo + (size_t)base * 4) = l;
    }
  }
}

// ---------------- transpose-convert: f32 [R][C] -> scale -> bf16 [C][R] ------
__device__ __forceinline__ void tconv_body(const float* __restrict__ src,
                                           bf16_t* __restrict__ hi,
                                           bf16_t* __restrict__ lo,
                                           int R, int C, int bx, int by,
                                           bool wantlo, float scale) {
  __shared__ float t[32][33];
  int c0 = bx * 32, r0 = by * 32;
  int tx = threadIdx.x & 31, ty = threadIdx.x >> 5;
#pragma unroll
  for (int rr = 0; rr < 4; rr++) {
    int r = ty + rr * 8;
    t[r][tx] = src[(size_t)(r0 + r) * C + c0 + tx];
  }
  __syncthreads();
#pragma unroll
  for (int rr = 0; rr < 4; rr++) {
    int cl = ty + rr * 8;
    float f = t[tx][cl] * scale;
    bf16_t h = (bf16_t)f;
    size_t oi = (size_t)(c0 + cl) * R + r0 + tx;
    hi[oi] = h;
    if (wantlo) lo[oi] = (bf16_t)(f - (float)h);
  }
}

__global__ __launch_bounds__(256) void k_tconv3(const float* __restrict__ Wk,
                                                const float* __restrict__ Wr,
                                                const float* __restrict__ aw,
                                                bf16_t* __restrict__ kt,
                                                bf16_t* __restrict__ rkt,
                                                bf16_t* __restrict__ awt) {
  int b = blockIdx.x;
  const float* src; bf16_t* hi; int R, C, bx, by;
  if (b < 384)       { src = Wk; hi = kt;  R = 256; C = 1536; bx = b % 48; by = b / 48; }
  else if (b < 1152) { b -= 384;  src = Wr; hi = rkt; R = 512; C = 1536; bx = b % 48; by = b / 48; }
  else               { b -= 1152; src = aw; hi = awt; R = 256; C = 512;  bx = b % 16; by = b / 16; }
  tconv_body(src, hi, nullptr, R, C, bx, by, false, 1.f);
}

// kx/kh pre-scaled by 1/(2pi): agg output is then directly in revolutions.
__global__ __launch_bounds__(256) void k_tconv2(const float* __restrict__ kx,
                                                const float* __restrict__ kh,
                                                bf16_t* __restrict__ kxh, bf16_t* __restrict__ kxl,
                                                bf16_t* __restrict__ khh, bf16_t* __restrict__ khl) {
  int b = blockIdx.x;
  const float* src; bf16_t *hi, *lo; int bx, by;
  if (b < 64) { src = kx; hi = kxh; lo = kxl; bx = b % 8; by = b / 8; }
  else        { b -= 64; src = kh; hi = khh; lo = khl; bx = b % 8; by = b / 8; }
  tconv_body(src, hi, lo, 256, 256, bx, by, true, INV2PI);
}

// ---------------- generic multi-pass bf16 MFMA GEMM (stride 64 + XOR swz) ---
// LDS 16B-slot s at row r lives at phys slot s^(r&7).
struct Pass { const bf16_t* A; const bf16_t* Bt; int K; int lda; int ldbt; };
struct GArgs {
  Pass p[6]; int np;
  const float* bias;
  int act;                  // 1 -> sigmoid(acc+bias)
  float* out; int ldout;
};

template<int BM, int BN>
__global__ __launch_bounds__(512) void k_gemm(GArgs g) {
  constexpr int MI = BM / 32;
  constexpr int NJ = BN / 64;
  constexpr int IA = (BM * 8) / 512;
  constexpr int IB = (BN * 8) / 512;
  __shared__ bf16_t smA[BM * 64];
  __shared__ bf16_t smB[BN * 64];
  const int tid = threadIdx.x;
  const int m0 = blockIdx.y * BM, n0 = blockIdx.x * BN;
  const int wv = tid >> 6, lane = tid & 63;
  const int wm = wv >> 2, wn = wv & 3;
  const int lr = lane & 15, g4 = lane >> 4;

  f32x4 acc[MI][NJ];
#pragma unroll
  for (int i = 0; i < MI; i++)
#pragma unroll
    for (int j = 0; j < NJ; j++) acc[i][j] = f32x4{0.f, 0.f, 0.f, 0.f};

  for (int ps = 0; ps < g.np; ps++) {
    const bf16_t* A = g.p[ps].A;
    const bf16_t* Bt = g.p[ps].Bt;
    const int K = g.p[ps].K, lda = g.p[ps].lda, ldbt = g.p[ps].ldbt;
    for (int k0 = 0; k0 < K; k0 += 64) {
      bf16x8 ar[IA], br[IB];
#pragma unroll
      for (int r = 0; r < IA; r++) {
        int task = tid + r * 512, row = task >> 3, t = task & 7, sf = t ^ (row & 7);
        ar[r] = *(const bf16x8*)(A + (size_t)(m0 + row) * lda + k0 + sf * 8);
      }
#pragma unroll
      for (int r = 0; r < IB; r++) {
        int task = tid + r * 512, row = task >> 3, t = task & 7, sf = t ^ (row & 7);
        br[r] = *(const bf16x8*)(Bt + (size_t)(n0 + row) * ldbt + k0 + sf * 8);
      }
      __syncthreads();
#pragma unroll
      for (int r = 0; r < IA; r++) {
        int task = tid + r * 512, row = task >> 3, t = task & 7;
        *(bf16x8*)(smA + row * 64 + t * 8) = ar[r];
      }
#pragma unroll
      for (int r = 0; r < IB; r++) {
        int task = tid + r * 512, row = task >> 3, t = task & 7;
        *(bf16x8*)(smB + row * 64 + t * 8) = br[r];
      }
      __syncthreads();
#pragma unroll
      for (int ks = 0; ks < 2; ks++) {
        bf16x8 af[MI], bfr[NJ];
#pragma unroll
        for (int i = 0; i < MI; i++) {
          int row = wm * (BM / 2) + i * 16 + lr;
          af[i] = *(const bf16x8*)(smA + row * 64 + ((ks * 4 + g4) ^ (lr & 7)) * 8);
        }
#pragma unroll
        for (int j = 0; j < NJ; j++) {
          int row = wn * (BN / 4) + j * 16 + lr;
          bfr[j] = *(const bf16x8*)(smB + row * 64 + ((ks * 4 + g4) ^ (lr & 7)) * 8);
        }
#pragma unroll
        for (int i = 0; i < MI; i++)
#pragma unroll
          for (int j = 0; j < NJ; j++)
            acc[i][j] = __builtin_amdgcn_mfma_f32_16x16x32_bf16(af[i], bfr[j], acc[i][j], 0, 0, 0);
      }
    }
  }
#pragma unroll
  for (int i = 0; i < MI; i++)
#pragma unroll
    for (int j = 0; j < NJ; j++) {
      int col = n0 + wn * (BN / 4) + j * 16 + lr;
      float bb = g.bias ? g.bias[col] : 0.f;
#pragma unroll
      for (int r = 0; r < 4; r++) {
        int row = m0 + wm * (BM / 2) + i * 16 + (lane >> 4) * 4 + r;
        float v = acc[i][j][r] + bb;
        if (g.act == 1) v = sigm(v);
        g.out[(size_t)row * g.ldout + col] = v;
      }
    }
}

// ---------------- fused gates GEMM + cell state (swizzled LDS) ----------------
struct GatesArgs {
  const bf16_t* xhi; const bf16_t* h0b; const bf16_t* kt; const bf16_t* rkt;
  const float* bias; const float* c0; float* c_out; float* tc;
};

__global__ __launch_bounds__(512, 2) void k_gates(GatesArgs ga) {
  __shared__ bf16_t smA[64 * 64];
  __shared__ bf16_t smB[3 * 128 * 64];
  const int tid = threadIdx.x;
  const int n0 = blockIdx.x * 128;
  const int m0 = blockIdx.y * 64;
  const int wv = tid >> 6, lane = tid & 63;
  const int wm = wv >> 2, wn = wv & 3;
  const int lr = lane & 15, g4 = lane >> 4;

  f32x4 acc[3][2][2];
#pragma unroll
  for (int t = 0; t < 3; t++)
#pragma unroll
    for (int i = 0; i < 2; i++)
#pragma unroll
      for (int j = 0; j < 2; j++) acc[t][i][j] = f32x4{0.f, 0.f, 0.f, 0.f};

  for (int ps = 0; ps < 2; ps++) {
    const bf16_t* A  = ps ? ga.h0b : ga.xhi;
    const bf16_t* Bt = ps ? ga.rkt : ga.kt;
    const int K = ps ? 512 : 256, ld = K;
    for (int k0 = 0; k0 < K; k0 += 64) {
      int arow = tid >> 3, at = tid & 7, asf = at ^ (arow & 7);
      bf16x8 ar = *(const bf16x8*)(A + (size_t)(m0 + arow) * ld + k0 + asf * 8);
      bf16x8 br[6];
#pragma unroll
      for (int r = 0; r < 6; r++) {
        int task = tid + r * 512;
        int gate = task >> 10, rem = task & 1023, o = rem >> 3, t = rem & 7, sf = t ^ (o & 7);
        br[r] = *(const bf16x8*)(Bt + (size_t)(gate * 512 + n0 + o) * ld + k0 + sf * 8);
      }
      __syncthreads();
      *(bf16x8*)(smA + arow * 64 + at * 8) = ar;
#pragma unroll
      for (int r = 0; r < 6; r++) {
        int task = tid + r * 512;
        int gate = task >> 10, rem = task & 1023, o = rem >> 3, t = rem & 7;
        *(bf16x8*)(smB + (gate * 128 + o) * 64 + t * 8) = br[r];
      }
      __syncthreads();
#pragma unroll
      for (int ks = 0; ks < 2; ks++) {
        bf16x8 af[2];
#pragma unroll
        for (int i = 0; i < 2; i++) {
          int row = wm * 32 + i * 16 + lr;
          af[i] = *(const bf16x8*)(smA + row * 64 + ((ks * 4 + g4) ^ (lr & 7)) * 8);
        }
#pragma unroll
        for (int t = 0; t < 3; t++) {
          bf16x8 bfr[2];
#pragma unroll
          for (int j = 0; j < 2; j++) {
            int row = wn * 32 + j * 16 + lr;
            bfr[j] = *(const bf16x8*)(smB + (t * 128 + row) * 64 + ((ks * 4 + g4) ^ (lr & 7)) * 8);
          }
#pragma unroll
          for (int i = 0; i < 2; i++)
#pragma unroll
            for (int j = 0; j < 2; j++)
              acc[t][i][j] = __builtin_amdgcn_mfma_f32_16x16x32_bf16(af[i], bfr[j], acc[t][i][j], 0, 0, 0);
        }
      }
    }
  }
#pragma unroll
  for (int i = 0; i < 2; i++)
#pragma unroll
    for (int j = 0; j < 2; j++) {
      int col = n0 + wn * 32 + j * 16 + lr;
      float bi = ga.bias[col], bf_ = ga.bias[512 + col], bc = ga.bias[1024 + col];
#pragma unroll
      for (int r = 0; r < 4; r++) {
        int row = m0 + wm * 32 + i * 16 + (lane >> 4) * 4 + r;
        size_t idx = (size_t)row * 512 + col;
        float iv = sigm(acc[0][i][j][r] + bi);
        float fv = sigm(acc[1][i][j][r] + bf_);
        float cc = sigm(acc[2][i][j][r] + bc);
        float cv = fv * ga.c0[idx] + iv * fast_tanh(cc);
        ga.c_out[idx] = cv;
        ga.tc[idx] = fast_tanh(cv);
      }
    }
}

// ---------------- Fourier-KAN GEMM v3 ----------------
// BM=64, BN=128, K-split q=4. Swizzled LDS (stride 64 + slot XOR), B staged
// via global_load_lds w/ pre-swizzled per-lane source, dbuf, 1 barrier/iter.
// agg is already in revolutions (kx/kh pre-scaled by 1/2pi).
__global__ __launch_bounds__(512, 4) void k_fourier(const float* __restrict__ agg,
                                                    const bf16_t* __restrict__ fcb,
                                                    float* __restrict__ P) {
  __shared__ float  zl[64 * 65];
  __shared__ bf16_t Asm[2][64 * 64];
  __shared__ bf16_t Bsm[2][128 * 64];
  const int tid = threadIdx.x;
  const int bx = blockIdx.x;                  // 512 blocks
  const int q = bx & 3, nb = (bx >> 2) & 1, mb = bx >> 3;
  const int m0 = mb * 64, n0 = nb * 128, i0 = q * 64;
  const int wv = tid >> 6, lane = tid & 63;
  const int wm = wv >> 2, wn = wv & 3;
  const int lr = lane & 15, g4 = lane >> 4;
  const int arow = tid >> 3, hq = tid & 7;

  // stage z tile [64 rows x 64 i] fp32 (revolutions)
#pragma unroll
  for (int r = 0; r < 2; r++) {
    int task = tid + r * 512, row = task >> 4, seg = task & 15;
    float4 v = *(const float4*)(agg + (size_t)(m0 + row) * 256 + i0 + seg * 4);
    zl[row * 65 + seg * 4 + 0] = v.x;
    zl[row * 65 + seg * 4 + 1] = v.y;
    zl[row * 65 + seg * 4 + 2] = v.z;
    zl[row * 65 + seg * 4 + 3] = v.w;
  }

  // B staging: linear LDS dest (wave chunk), pre-swizzled global source.
  // linear slot16 p = row*8 + t  with row = 64c + 8w + (l>>3), t = l&7;
  // logical seg fetched = t ^ (row&7) = (l&7)^(l>>3).
  const int lrow8 = lane >> 3, lt = lane & 7;
  const int segB = lt ^ lrow8, sB = segB >> 2, gB = (segB & 3) * 8;
  const bf16_t* gp0 = fcb + (size_t)sB * 2097152 +
                      (size_t)(n0 + wv * 8 + lrow8) * 8192 + (size_t)i0 * 32 + gB;
  const bf16_t* gp1 = gp0 + (size_t)64 * 8192;
  const int ldsWaveOff = wv * 512;            // elems (64 slots16/wave-chunk)

  auto stageB = [&](const bf16_t* ga, const bf16_t* gb, bf16_t* Bb) {
#if HAVE_GLDS
    __builtin_amdgcn_global_load_lds((const __attribute__((address_space(1))) void*)ga,
                                     (__attribute__((address_space(3))) void*)(Bb + ldsWaveOff),
                                     16, 0, 0);
    __builtin_amdgcn_global_load_lds((const __attribute__((address_space(1))) void*)gb,
                                     (__attribute__((address_space(3))) void*)(Bb + 4096 + ldsWaveOff),
                                     16, 0, 0);
#else
    bf16x8 va = *(const bf16x8*)ga, vb = *(const bf16x8*)gb;
    *(bf16x8*)(Bb + ldsWaveOff + lane * 8) = va;
    *(bf16x8*)(Bb + 4096 + ldsWaveOff + lane * 8) = vb;
#endif
  };

  // A generation: logical cos at elems [0..31] (k=g+1), sin at [32..63].
  const float* zp = zl + arow * 65;
  const int csl = (((hq >> 1) ^ (arow & 7)) * 8) + (hq & 1) * 4;
  const int ssl = (((4 + (hq >> 1)) ^ (arow & 7)) * 8) + (hq & 1) * 4;
  auto genA = [&](int ii, bf16_t* Ab) {
    float zr = zp[ii];
    bf16x4 cv, sv;
#pragma unroll
    for (int t = 0; t < 4; t++) {
      float rev = fractf(zr * (float)(hq * 4 + t + 1));
      cv[t] = (bf16_t)cos_rev(rev);
      sv[t] = (bf16_t)sin_rev(rev);
    }
    bf16_t* rb = Ab + arow * 64;
    *(bf16x4*)(rb + csl) = cv;
    *(bf16x4*)(rb + ssl) = sv;
  };

  // fragment LDS element offsets (fixed per thread)
  int offA[2][2], offB[2][2];
#pragma unroll
  for (int ks = 0; ks < 2; ks++) {
#pragma unroll
    for (int i = 0; i < 2; i++) {
      int row = wm * 32 + i * 16 + lr;
      offA[ks][i] = row * 64 + ((ks * 4 + g4) ^ (lr & 7)) * 8;
    }
#pragma unroll
    for (int j = 0; j < 2; j++) {
      int row = wn * 32 + j * 16 + lr;
      offB[ks][j] = row * 64 + ((ks * 4 + g4) ^ (lr & 7)) * 8;
    }
  }

  f32x4 acc[2][2];
#pragma unroll
  for (int i = 0; i < 2; i++)
#pragma unroll
    for (int j = 0; j < 2; j++) acc[i][j] = f32x4{0.f, 0.f, 0.f, 0.f};

  __syncthreads();                            // zl ready
  stageB(gp0, gp1, Bsm[0]); gp0 += 32; gp1 += 32;
  genA(0, Asm[0]);
  __syncthreads();                            // (compiler drains vmcnt here)

  for (int ii = 0; ii < 64; ii++) {
    bf16_t* Ac = Asm[ii & 1];
    bf16_t* Bc = Bsm[ii & 1];
    if (ii < 63) { stageB(gp0, gp1, Bsm[(ii & 1) ^ 1]); gp0 += 32; gp1 += 32; }
    bf16x8 af[2][2], bfr[2][2];
#pragma unroll
    for (int ks = 0; ks < 2; ks++) {
#pragma unroll
      for (int i = 0; i < 2; i++) af[ks][i] = *(const bf16x8*)(Ac + offA[ks][i]);
#pragma unroll
      for (int j = 0; j < 2; j++) bfr[ks][j] = *(const bf16x8*)(Bc + offB[ks][j]);
    }
    if (ii < 63) genA(ii + 1, Asm[(ii & 1) ^ 1]);   // VALU overlaps ds latency
#pragma unroll
    for (int ks = 0; ks < 2; ks++)
#pragma unroll
      for (int i = 0; i < 2; i++)
#pragma unroll
        for (int j = 0; j < 2; j++)
          acc[i][j] = __builtin_amdgcn_mfma_f32_16x16x32_bf16(af[ks][i], bfr[ks][j], acc[i][j], 0, 0, 0);
    __syncthreads();
  }

  float* outp = P + (size_t)q * 1048576;
#pragma unroll
  for (int i = 0; i < 2; i++)
#pragma unroll
    for (int j = 0; j < 2; j++) {
      int col = n0 + wn * 32 + j * 16 + lr;
#pragma unroll
      for (int r = 0; r < 4; r++) {
        int row = m0 + wm * 32 + i * 16 + (lane >> 4) * 4 + r;
        outp[(size_t)row * 256 + col] = acc[i][j][r];
      }
    }
}

// ---------------- reduce K-split partials + new_s epilogue (float4) ---------
__global__ __launch_bounds__(256) void k_freduce(const float* __restrict__ P,
                                                 const float* __restrict__ fb,
                                                 const float* __restrict__ tk,
                                                 const float* __restrict__ s0,
                                                 float* __restrict__ news,
                                                 bf16_t* __restrict__ sob) {
  int stride = gridDim.x * blockDim.x;
  const float4* P4 = (const float4*)P;
  for (int qd = blockIdx.x * blockDim.x + threadIdx.x; qd < 262144; qd += stride) {
    int i = qd * 4, o = i & 255;
    float4 a = P4[qd], b = P4[qd + 262144], c = P4[qd + 524288], d = P4[qd + 786432];
    float4 s = *(const float4*)(s0 + i);
    float v0 = a.x + b.x + c.x + d.x + fb[o + 0];
    float v1 = a.y + b.y + c.y + d.y + fb[o + 1];
    float v2 = a.z + b.z + c.z + d.z + fb[o + 2];
    float v3 = a.w + b.w + c.w + d.w + fb[o + 3];
    bf16x4 sb; sb[0] = (bf16_t)v0; sb[1] = (bf16_t)v1; sb[2] = (bf16_t)v2; sb[3] = (bf16_t)v3;
    *(bf16x4*)(sob + i) = sb;
    float4 ns;
    ns.x = tk[o + 0] * v0 + tk[256 + o + 0] * s.x;
    ns.y = tk[o + 1] * v1 + tk[256 + o + 1] * s.y;
    ns.z = tk[o + 2] * v2 + tk[256 + o + 2] * s.z;
    ns.w = tk[o + 3] * v3 + tk[256 + o + 3] * s.w;
    *(float4*)(news + i) = ns;
  }
}

// ---------------- h = LN(o * tanh(c)) ----------------
__global__ __launch_bounds__(256) void k_ln(const float* __restrict__ o,
                                            const float* __restrict__ tc,
                                            const float* __restrict__ lg,
                                            const float* __restrict__ lb,
                                            float* __restrict__ h) {
  int b = blockIdx.x, tid = threadIdx.x;
  float2 ov = *(const float2*)(o + (size_t)b * 512 + tid * 2);
  float2 tv = *(const float2*)(tc + (size_t)b * 512 + tid * 2);
  float h0 = ov.x * tv.x, h1 = ov.y * tv.y;
  float s = h0 + h1, ss = h0 * h0 + h1 * h1;
#pragma unroll
  for (int off = 32; off; off >>= 1) {
    s += __shfl_xor(s, off);
    ss += __shfl_xor(ss, off);
  }
  __shared__ float red[8];
  int wid = tid >> 6;
  if ((tid & 63) == 0) { red[wid] = s; red[4 + wid] = ss; }
  __syncthreads();
  s = red[0] + red[1] + red[2] + red[3];
  ss = red[4] + red[5] + red[6] + red[7];
  float mu = s * (1.f / 512.f);
  float var = ss * (1.f / 512.f) - mu * mu;
  float rs = rsqrtf(var + 1e-5f);
  int j = tid * 2;
  h[(size_t)b * 512 + j]     = (h0 - mu) * rs * lg[j]     + lb[j];
  h[(size_t)b * 512 + j + 1] = (h1 - mu) * rs * lg[j + 1] + lb[j + 1];
}

// ---------------- launcher ----------------
extern "C" void kernel_launch(void* const* d_in, const int* in_sizes, int n_in,
                              void* d_out, int out_size, void* d_ws, size_t ws_size,
                              hipStream_t stream) {
  const float* x    = (const float*)d_in[0];
  const float* h0   = (const float*)d_in[1];
  const float* c0   = (const float*)d_in[2];
  const float* s0   = (const float*)d_in[3];
  const float* Wk   = (const float*)d_in[4];
  const float* Wr   = (const float*)d_in[5];
  const float* bias = (const float*)d_in[6];
  const float* kx   = (const float*)d_in[7];
  const float* kh   = (const float*)d_in[8];
  const float* tk   = (const float*)d_in[9];
  const float* fc   = (const float*)d_in[10];
  const float* fb   = (const float*)d_in[11];
  const float* aw   = (const float*)d_in[12];
  const float* ab   = (const float*)d_in[13];
  const float* lg   = (const float*)d_in[14];
  const float* lbp  = (const float*)d_in[15];
  float* out = (float*)d_out;
  char* ws = (char*)d_ws;
  auto BF = [&](unsigned long long off) { return (bf16_t*)(ws + off); };
  auto FP = [&](unsigned long long off) { return (float*)(ws + off); };

  k_prep<<<2048, 256, 0, stream>>>(x, h0, s0, fc, BF(O_XHI), BF(O_XLO), BF(O_H0),
                                   BF(O_S0H), BF(O_S0L), BF(O_FCB));
  k_tconv3<<<1280, 256, 0, stream>>>(Wk, Wr, aw, BF(O_KT), BF(O_RKT), BF(O_AWT));
  k_tconv2<<<128, 256, 0, stream>>>(kx, kh, BF(O_KXH), BF(O_KXL), BF(O_KHH), BF(O_KHL));

  // fused gates GEMM + cell: c -> d_out[2M..4M), tanh(c) -> TC
  {
    GatesArgs ga{ BF(O_XHI), BF(O_H0), BF(O_KT), BF(O_RKT), bias, c0,
                  out + 2097152, FP(O_TC) };
    k_gates<<<dim3(4, 64), 512, 0, stream>>>(ga);
  }

  // agg GEMM (hi/lo split), output in revolutions
  {
    GArgs g{};
    g.p[0] = { BF(O_XHI), BF(O_KXH), 256, 256, 256 };
    g.p[1] = { BF(O_XHI), BF(O_KXL), 256, 256, 256 };
    g.p[2] = { BF(O_XLO), BF(O_KXH), 256, 256, 256 };
    g.p[3] = { BF(O_S0H), BF(O_KHH), 256, 256, 256 };
    g.p[4] = { BF(O_S0H), BF(O_KHL), 256, 256, 256 };
    g.p[5] = { BF(O_S0L), BF(O_KHH), 256, 256, 256 };
    g.np = 6; g.bias = nullptr; g.act = 0;
    g.out = FP(O_AGG); g.ldout = 256;
    k_gemm<64, 64><<<dim3(4, 64), 512, 0, stream>>>(g);
  }
  // Fourier KAN (K-split x4, 512 blocks)
  k_fourier<<<512, 512, 0, stream>>>(FP(O_AGG), BF(O_FCB), FP(O_P));
  // reduce partials, emit new_s (d_out[4M..5M)) + sub_out bf16
  k_freduce<<<1024, 256, 0, stream>>>(FP(O_P), fb, tk, s0, out + 4194304, BF(O_SOB));

  // out-proj GEMM: o = sigmoid(sub_out@agg_w + agg_b)   (O overlays FCB)
  {
    GArgs g{};
    g.p[0] = { BF(O_SOB), BF(O_AWT), 256, 256, 256 };
    g.np = 1; g.bias = ab; g.act = 1;
    g.out = FP(O_O); g.ldout = 512;
    k_gemm<64, 128><<<dim3(4, 64), 512, 0, stream>>>(g);
  }
  // h = LN(o * tanh(c)) -> d_out[0..2M)
  k_ln<<<4096, 256, 0, stream>>>(FP(O_O), FP(O_TC), lg, lbp, out);
}

// Round 6
// 125.755 us; speedup vs baseline: 1.4073x; 1.0305x over previous
//
#include <hip/hip_runtime.h>
#include <hip/hip_bf16.h>

typedef __bf16 bf16_t;
typedef __bf16 bf16x4 __attribute__((ext_vector_type(4)));
typedef __bf16 bf16x8 __attribute__((ext_vector_type(8)));
typedef float  f32x4  __attribute__((ext_vector_type(4)));

#define NB 4096
#define IN_DIM 256
#define HID 512
#define SUB 256
#define GRID_ 32

#if __has_builtin(__builtin_amdgcn_global_load_lds)
#define HAVE_GLDS 1
#else
#define HAVE_GLDS 0
#endif

// ---------------- math helpers ----------------
__device__ __forceinline__ float fract_f(float x) {
#if __has_builtin(__builtin_amdgcn_fractf)
  return __builtin_amdgcn_fractf(x);
#else
  return x - floorf(x);
#endif
}
__device__ __forceinline__ float cos_rev(float rev) {   // input: revolutions in [0,1)
#if __has_builtin(__builtin_amdgcn_cosf)
  return __builtin_amdgcn_cosf(rev);
#else
  return __cosf(rev * 6.283185307179586f);
#endif
}
__device__ __forceinline__ float sin_rev(float rev) {
#if __has_builtin(__builtin_amdgcn_sinf)
  return __builtin_amdgcn_sinf(rev);
#else
  return __sinf(rev * 6.283185307179586f);
#endif
}
__device__ __forceinline__ float sigm(float v) { return 1.f / (1.f + __expf(-v)); }
__device__ __forceinline__ float fast_tanh(float x) {
  float e = __expf(2.f * x);
  return (e - 1.f) / (e + 1.f);
}
#define INV2PI 0.15915494309189535f

// ---------------- workspace layout (bytes), high-water 59.77MB (== r2's) ----
// P partial chunks 0-2 overlay XHI/XLO, H0, S0H/S0L (dead after agg GEMM,
// which completes before k_fourier). O overlays FCB (dead after k_fourier).
#define O_XHI   0ull
#define O_XLO   2097152ull
#define O_H0    4194304ull
#define O_S0H   8388608ull
#define O_S0L   10485760ull
#define O_FCB   12582912ull
#define O_O     12582912ull
#define O_KT    20971520ull
#define O_RKT   21757952ull
#define O_AWT   23330816ull
#define O_KXH   23592960ull
#define O_KXL   23724032ull
#define O_KHH   23855104ull
#define O_KHL   23986176ull
#define O_TC    24117248ull
#define O_SOB   32505856ull
#define O_AGG   34603008ull
#define O_P3    38797312ull   // chunks 3..7, 5 x 4MB -> end 59768832

// ---------------- fused plain conversions (float4) ----------------
__global__ __launch_bounds__(256) void k_prep(const float* __restrict__ x,
                                              const float* __restrict__ h0,
                                              const float* __restrict__ s0,
                                              const float* __restrict__ fc,
                                              bf16_t* __restrict__ xhi, bf16_t* __restrict__ xlo,
                                              bf16_t* __restrict__ h0b,
                                              bf16_t* __restrict__ s0h, bf16_t* __restrict__ s0l,
                                              bf16_t* __restrict__ fcb) {
  int stride = gridDim.x * blockDim.x;
  for (int q = blockIdx.x * blockDim.x + threadIdx.x; q < 2097152; q += stride) {
    const float* src; bf16_t* hi; bf16_t* lo = nullptr; int base;
    if (q < 262144)       { src = x;  hi = xhi; lo = xlo; base = q; }
    else if (q < 786432)  { src = h0; hi = h0b;           base = q - 262144; }
    else if (q < 1048576) { src = s0; hi = s0h; lo = s0l; base = q - 786432; }
    else                  { src = fc; hi = fcb;           base = q - 1048576; }
    float4 v = *(const float4*)(src + (size_t)base * 4);
    bf16x4 h; h[0] = (bf16_t)v.x; h[1] = (bf16_t)v.y; h[2] = (bf16_t)v.z; h[3] = (bf16_t)v.w;
    *(bf16x4*)(hi + (size_t)base * 4) = h;
    if (lo) {
      bf16x4 l;
      l[0] = (bf16_t)(v.x - (float)h[0]); l[1] = (bf16_t)(v.y - (float)h[1]);
      l[2] = (bf16_t)(v.z - (float)h[2]); l[3] = (bf16_t)(v.w - (float)h[3]);
      *(bf16x4*)(lo + (size_t)base * 4) = l;
    }
  }
}

// ---------------- transpose-convert: f32 [R][C] -> scale -> bf16 [C][R] ------
__device__ __forceinline__ void tconv_body(const float* __restrict__ src,
                                           bf16_t* __restrict__ hi,
                                           bf16_t* __restrict__ lo,
                                           int R, int C, int bx, int by,
                                           bool wantlo, float scale) {
  __shared__ float t[32][33];
  int c0 = bx * 32, r0 = by * 32;
  int tx = threadIdx.x & 31, ty = threadIdx.x >> 5;
#pragma unroll
  for (int rr = 0; rr < 4; rr++) {
    int r = ty + rr * 8;
    t[r][tx] = src[(size_t)(r0 + r) * C + c0 + tx];
  }
  __syncthreads();
#pragma unroll
  for (int rr = 0; rr < 4; rr++) {
    int cl = ty + rr * 8;
    float f = t[tx][cl] * scale;
    bf16_t h = (bf16_t)f;
    size_t oi = (size_t)(c0 + cl) * R + r0 + tx;
    hi[oi] = h;
    if (wantlo) lo[oi] = (bf16_t)(f - (float)h);
  }
}

// All 5 weight transposes in one launch (1408 blocks).
__global__ __launch_bounds__(256) void k_tconv(const float* __restrict__ Wk,
                                               const float* __restrict__ Wr,
                                               const float* __restrict__ aw,
                                               const float* __restrict__ kx,
                                               const float* __restrict__ kh,
                                               bf16_t* __restrict__ kt,
                                               bf16_t* __restrict__ rkt,
                                               bf16_t* __restrict__ awt,
                                               bf16_t* __restrict__ kxh, bf16_t* __restrict__ kxl,
                                               bf16_t* __restrict__ khh, bf16_t* __restrict__ khl) {
  int b = blockIdx.x;
  if (b < 384)       { tconv_body(Wk, kt,  nullptr, 256, 1536, b % 48, b / 48, false, 1.f); }
  else if (b < 1152) { b -= 384;  tconv_body(Wr, rkt, nullptr, 512, 1536, b % 48, b / 48, false, 1.f); }
  else if (b < 1280) { b -= 1152; tconv_body(aw, awt, nullptr, 256, 512,  b % 16, b / 16, false, 1.f); }
  else if (b < 1344) { b -= 1280; tconv_body(kx, kxh, kxl,     256, 256,  b % 8,  b / 8,  true, INV2PI); }
  else               { b -= 1344; tconv_body(kh, khh, khl,     256, 256,  b % 8,  b / 8,  true, INV2PI); }
}

// ---------------- generic multi-pass bf16 MFMA GEMM (stride 64 + XOR swz) ---
struct Pass { const bf16_t* A; const bf16_t* Bt; int K; int lda; int ldbt; };
struct GArgs {
  Pass p[6]; int np;
  const float* bias;
  int act;                  // 1 -> sigmoid(acc+bias)
  float* out; int ldout;
};

template<int BM, int BN>
__global__ __launch_bounds__(512) void k_gemm(GArgs g) {
  constexpr int MI = BM / 32;
  constexpr int NJ = BN / 64;
  constexpr int IA = (BM * 8) / 512;
  constexpr int IB = (BN * 8) / 512;
  __shared__ bf16_t smA[BM * 64];
  __shared__ bf16_t smB[BN * 64];
  const int tid = threadIdx.x;
  const int m0 = blockIdx.y * BM, n0 = blockIdx.x * BN;
  const int wv = tid >> 6, lane = tid & 63;
  const int wm = wv >> 2, wn = wv & 3;
  const int lr = lane & 15, g4 = lane >> 4;

  f32x4 acc[MI][NJ];
#pragma unroll
  for (int i = 0; i < MI; i++)
#pragma unroll
    for (int j = 0; j < NJ; j++) acc[i][j] = f32x4{0.f, 0.f, 0.f, 0.f};

  for (int ps = 0; ps < g.np; ps++) {
    const bf16_t* A = g.p[ps].A;
    const bf16_t* Bt = g.p[ps].Bt;
    const int K = g.p[ps].K, lda = g.p[ps].lda, ldbt = g.p[ps].ldbt;
    for (int k0 = 0; k0 < K; k0 += 64) {
      bf16x8 ar[IA], br[IB];
#pragma unroll
      for (int r = 0; r < IA; r++) {
        int task = tid + r * 512, row = task >> 3, t = task & 7, sf = t ^ (row & 7);
        ar[r] = *(const bf16x8*)(A + (size_t)(m0 + row) * lda + k0 + sf * 8);
      }
#pragma unroll
      for (int r = 0; r < IB; r++) {
        int task = tid + r * 512, row = task >> 3, t = task & 7, sf = t ^ (row & 7);
        br[r] = *(const bf16x8*)(Bt + (size_t)(n0 + row) * ldbt + k0 + sf * 8);
      }
      __syncthreads();
#pragma unroll
      for (int r = 0; r < IA; r++) {
        int task = tid + r * 512, row = task >> 3, t = task & 7;
        *(bf16x8*)(smA + row * 64 + t * 8) = ar[r];
      }
#pragma unroll
      for (int r = 0; r < IB; r++) {
        int task = tid + r * 512, row = task >> 3, t = task & 7;
        *(bf16x8*)(smB + row * 64 + t * 8) = br[r];
      }
      __syncthreads();
#pragma unroll
      for (int ks = 0; ks < 2; ks++) {
        bf16x8 af[MI], bfr[NJ];
#pragma unroll
        for (int i = 0; i < MI; i++) {
          int row = wm * (BM / 2) + i * 16 + lr;
          af[i] = *(const bf16x8*)(smA + row * 64 + ((ks * 4 + g4) ^ (lr & 7)) * 8);
        }
#pragma unroll
        for (int j = 0; j < NJ; j++) {
          int row = wn * (BN / 4) + j * 16 + lr;
          bfr[j] = *(const bf16x8*)(smB + row * 64 + ((ks * 4 + g4) ^ (lr & 7)) * 8);
        }
#pragma unroll
        for (int i = 0; i < MI; i++)
#pragma unroll
          for (int j = 0; j < NJ; j++)
            acc[i][j] = __builtin_amdgcn_mfma_f32_16x16x32_bf16(af[i], bfr[j], acc[i][j], 0, 0, 0);
      }
    }
  }
#pragma unroll
  for (int i = 0; i < MI; i++)
#pragma unroll
    for (int j = 0; j < NJ; j++) {
      int col = n0 + wn * (BN / 4) + j * 16 + lr;
      float bb = g.bias ? g.bias[col] : 0.f;
#pragma unroll
      for (int r = 0; r < 4; r++) {
        int row = m0 + wm * (BM / 2) + i * 16 + (lane >> 4) * 4 + r;
        float v = acc[i][j][r] + bb;
        if (g.act == 1) v = sigm(v);
        g.out[(size_t)row * g.ldout + col] = v;
      }
    }
}

// ---------------- fused gates GEMM + cell state (swizzled LDS) ----------------
struct GatesArgs {
  const bf16_t* xhi; const bf16_t* h0b; const bf16_t* kt; const bf16_t* rkt;
  const float* bias; const float* c0; float* c_out; float* tc;
};

__global__ __launch_bounds__(512, 2) void k_gates(GatesArgs ga) {
  __shared__ bf16_t smA[64 * 64];
  __shared__ bf16_t smB[3 * 128 * 64];
  const int tid = threadIdx.x;
  const int n0 = blockIdx.x * 128;
  const int m0 = blockIdx.y * 64;
  const int wv = tid >> 6, lane = tid & 63;
  const int wm = wv >> 2, wn = wv & 3;
  const int lr = lane & 15, g4 = lane >> 4;

  f32x4 acc[3][2][2];
#pragma unroll
  for (int t = 0; t < 3; t++)
#pragma unroll
    for (int i = 0; i < 2; i++)
#pragma unroll
      for (int j = 0; j < 2; j++) acc[t][i][j] = f32x4{0.f, 0.f, 0.f, 0.f};

  for (int ps = 0; ps < 2; ps++) {
    const bf16_t* A  = ps ? ga.h0b : ga.xhi;
    const bf16_t* Bt = ps ? ga.rkt : ga.kt;
    const int K = ps ? 512 : 256, ld = K;
    for (int k0 = 0; k0 < K; k0 += 64) {
      int arow = tid >> 3, at = tid & 7, asf = at ^ (arow & 7);
      bf16x8 ar = *(const bf16x8*)(A + (size_t)(m0 + arow) * ld + k0 + asf * 8);
      bf16x8 br[6];
#pragma unroll
      for (int r = 0; r < 6; r++) {
        int task = tid + r * 512;
        int gate = task >> 10, rem = task & 1023, o = rem >> 3, t = rem & 7, sf = t ^ (o & 7);
        br[r] = *(const bf16x8*)(Bt + (size_t)(gate * 512 + n0 + o) * ld + k0 + sf * 8);
      }
      __syncthreads();
      *(bf16x8*)(smA + arow * 64 + at * 8) = ar;
#pragma unroll
      for (int r = 0; r < 6; r++) {
        int task = tid + r * 512;
        int gate = task >> 10, rem = task & 1023, o = rem >> 3, t = rem & 7;
        *(bf16x8*)(smB + (gate * 128 + o) * 64 + t * 8) = br[r];
      }
      __syncthreads();
#pragma unroll
      for (int ks = 0; ks < 2; ks++) {
        bf16x8 af[2];
#pragma unroll
        for (int i = 0; i < 2; i++) {
          int row = wm * 32 + i * 16 + lr;
          af[i] = *(const bf16x8*)(smA + row * 64 + ((ks * 4 + g4) ^ (lr & 7)) * 8);
        }
#pragma unroll
        for (int t = 0; t < 3; t++) {
          bf16x8 bfr[2];
#pragma unroll
          for (int j = 0; j < 2; j++) {
            int row = wn * 32 + j * 16 + lr;
            bfr[j] = *(const bf16x8*)(smB + (t * 128 + row) * 64 + ((ks * 4 + g4) ^ (lr & 7)) * 8);
          }
#pragma unroll
          for (int i = 0; i < 2; i++)
#pragma unroll
            for (int j = 0; j < 2; j++)
              acc[t][i][j] = __builtin_amdgcn_mfma_f32_16x16x32_bf16(af[i], bfr[j], acc[t][i][j], 0, 0, 0);
        }
      }
    }
  }
#pragma unroll
  for (int i = 0; i < 2; i++)
#pragma unroll
    for (int j = 0; j < 2; j++) {
      int col = n0 + wn * 32 + j * 16 + lr;
      float bi = ga.bias[col], bf_ = ga.bias[512 + col], bc = ga.bias[1024 + col];
#pragma unroll
      for (int r = 0; r < 4; r++) {
        int row = m0 + wm * 32 + i * 16 + (lane >> 4) * 4 + r;
        size_t idx = (size_t)row * 512 + col;
        float iv = sigm(acc[0][i][j][r] + bi);
        float fv = sigm(acc[1][i][j][r] + bf_);
        float cc = sigm(acc[2][i][j][r] + bc);
        float cv = fv * ga.c0[idx] + iv * fast_tanh(cc);
        ga.c_out[idx] = cv;
        ga.tc[idx] = fast_tanh(cv);
      }
    }
}

// ---------------- Fourier-KAN GEMM v4: 64x64 wave-tiles (32 FLOP/LDS-byte) --
// BM=128, BN=256 (full N), q=8 K-split (i-chunk 32), grid 256 = 1 block/CU.
// 8 waves 2x4, acc[4][4]; dbuf LDS, 1 barrier/iter; B via global_load_lds
// with pre-swizzled per-lane source; A trig-generated, swizzled writes.
struct FArgs { const float* agg; const bf16_t* fcb; float* P[8]; };

__global__ __launch_bounds__(512, 2) void k_fourier(FArgs fa) {
  __shared__ float  zl[128 * 33];
  __shared__ bf16_t Asm[2][128 * 64];
  __shared__ bf16_t Bsm[2][256 * 64];
  const int tid = threadIdx.x;
  const int bx = blockIdx.x;                  // 256 blocks
  const int q = bx & 7, mb = bx >> 3;
  const int m0 = mb * 128, i0 = q * 32;
  const int wv = tid >> 6, lane = tid & 63;
  const int wm = wv >> 2, wn = wv & 3;
  const int lr = lane & 15, g4 = lane >> 4;

  // stage z tile [128 rows x 32 i] fp32 (already revolutions)
#pragma unroll
  for (int r = 0; r < 2; r++) {
    int task = tid + r * 512, row = task >> 3, seg = task & 7;
    float4 v = *(const float4*)(fa.agg + (size_t)(m0 + row) * 256 + i0 + seg * 4);
    zl[row * 33 + seg * 4 + 0] = v.x;
    zl[row * 33 + seg * 4 + 1] = v.y;
    zl[row * 33 + seg * 4 + 2] = v.z;
    zl[row * 33 + seg * 4 + 3] = v.w;
  }

  // B staging: per wave 32 rows (wv*32..+31), 4 glds/iter; linear LDS dest,
  // pre-swizzled global source seg = (lane&7)^(lane>>3).
  const int l8 = lane >> 3, lt = lane & 7;
  const int segB = lt ^ l8, sB = segB >> 2, gqB = (segB & 3) * 8;
  const bf16_t* gpB[4];
#pragma unroll
  for (int g = 0; g < 4; g++)
    gpB[g] = fa.fcb + (size_t)sB * 2097152 +
             (size_t)(wv * 32 + g * 8 + l8) * 8192 + (size_t)i0 * 32 + gqB;
  const int ldsOff = wv * 2048;               // + g*512 + lane*8 elems

  auto stageB = [&](int ii, bf16_t* Bb) {
#pragma unroll
    for (int g = 0; g < 4; g++) {
#if HAVE_GLDS
      __builtin_amdgcn_global_load_lds(
          (const __attribute__((address_space(1))) void*)(gpB[g] + ii * 32),
          (__attribute__((address_space(3))) void*)(Bb + ldsOff + g * 512),
          16, 0, 0);
#else
      bf16x8 v = *(const bf16x8*)(gpB[g] + ii * 32);
      *(bf16x8*)(Bb + ldsOff + g * 512 + lane * 8) = v;
#endif
    }
  };

  // A generation: 128 rows x 64 elems (32 cos | 32 sin); thread covers one
  // row-octet pair: arow = tid>>2, hq = tid&3 -> g in [8hq, 8hq+7].
  const int arow = tid >> 2, hq = tid & 3;
  const float* zp = zl + arow * 33;
  const int cOff = arow * 64 + ((hq       ^ (arow & 7)) * 8);
  const int sOff = arow * 64 + (((4 + hq) ^ (arow & 7)) * 8);
  auto genA = [&](int ii, bf16_t* Ab) {
    float zr = zp[ii];
    bf16x8 cv, sv;
#pragma unroll
    for (int t = 0; t < 8; t++) {
      float rev = fract_f(zr * (float)(hq * 8 + t + 1));
      cv[t] = (bf16_t)cos_rev(rev);
      sv[t] = (bf16_t)sin_rev(rev);
    }
    *(bf16x8*)(Ab + cOff) = cv;
    *(bf16x8*)(Ab + sOff) = sv;
  };

  // fixed fragment LDS offsets
  int offA[2][4], offB[2][4];
#pragma unroll
  for (int ks = 0; ks < 2; ks++) {
#pragma unroll
    for (int i = 0; i < 4; i++) {
      int row = wm * 64 + i * 16 + lr;
      offA[ks][i] = row * 64 + ((ks * 4 + g4) ^ (lr & 7)) * 8;
    }
#pragma unroll
    for (int j = 0; j < 4; j++) {
      int row = wn * 64 + j * 16 + lr;
      offB[ks][j] = row * 64 + ((ks * 4 + g4) ^ (lr & 7)) * 8;
    }
  }

  f32x4 acc[4][4];
#pragma unroll
  for (int i = 0; i < 4; i++)
#pragma unroll
    for (int j = 0; j < 4; j++) acc[i][j] = f32x4{0.f, 0.f, 0.f, 0.f};

  __syncthreads();                            // zl ready
  stageB(0, Bsm[0]);
  genA(0, Asm[0]);
  __syncthreads();                            // drains vmcnt + A visible

  for (int ii = 0; ii < 32; ii++) {
    const int cur = ii & 1;
    bf16_t* Ac = Asm[cur];
    bf16_t* Bc = Bsm[cur];
    if (ii < 31) stageB(ii + 1, Bsm[cur ^ 1]);
    bf16x8 af[2][4], bfr[2][4];
#pragma unroll
    for (int ks = 0; ks < 2; ks++) {
#pragma unroll
      for (int i = 0; i < 4; i++) af[ks][i] = *(const bf16x8*)(Ac + offA[ks][i]);
#pragma unroll
      for (int j = 0; j < 4; j++) bfr[ks][j] = *(const bf16x8*)(Bc + offB[ks][j]);
    }
    if (ii < 31) genA(ii + 1, Asm[cur ^ 1]);  // VALU/trans overlaps ds latency
#pragma unroll
    for (int ks = 0; ks < 2; ks++)
#pragma unroll
      for (int i = 0; i < 4; i++)
#pragma unroll
        for (int j = 0; j < 4; j++)
          acc[i][j] = __builtin_amdgcn_mfma_f32_16x16x32_bf16(af[ks][i], bfr[ks][j], acc[i][j], 0, 0, 0);
    __syncthreads();
  }

  float* outp = fa.P[q];
#pragma unroll
  for (int i = 0; i < 4; i++)
#pragma unroll
    for (int j = 0; j < 4; j++) {
      int col = wn * 64 + j * 16 + lr;
#pragma unroll
      for (int r = 0; r < 4; r++) {
        int row = m0 + wm * 64 + i * 16 + g4 * 4 + r;
        outp[(size_t)row * 256 + col] = acc[i][j][r];
      }
    }
}

// ---------------- reduce 8 K-split partials + new_s epilogue (float4) -------
struct RArgs {
  const float* P[8];
  const float* fb; const float* tk; const float* s0;
  float* news; bf16_t* sob;
};

__global__ __launch_bounds__(256) void k_freduce(RArgs ra) {
  int stride = gridDim.x * blockDim.x;
  for (int qd = blockIdx.x * blockDim.x + threadIdx.x; qd < 262144; qd += stride) {
    int i = qd * 4, o = i & 255;
    float4 v = *(const float4*)(ra.P[0] + i);
#pragma unroll
    for (int c = 1; c < 8; c++) {
      float4 p = *(const float4*)(ra.P[c] + i);
      v.x += p.x; v.y += p.y; v.z += p.z; v.w += p.w;
    }
    v.x += ra.fb[o + 0]; v.y += ra.fb[o + 1]; v.z += ra.fb[o + 2]; v.w += ra.fb[o + 3];
    bf16x4 sb; sb[0] = (bf16_t)v.x; sb[1] = (bf16_t)v.y; sb[2] = (bf16_t)v.z; sb[3] = (bf16_t)v.w;
    *(bf16x4*)(ra.sob + i) = sb;
    float4 s = *(const float4*)(ra.s0 + i);
    float4 ns;
    ns.x = ra.tk[o + 0] * v.x + ra.tk[256 + o + 0] * s.x;
    ns.y = ra.tk[o + 1] * v.y + ra.tk[256 + o + 1] * s.y;
    ns.z = ra.tk[o + 2] * v.z + ra.tk[256 + o + 2] * s.z;
    ns.w = ra.tk[o + 3] * v.w + ra.tk[256 + o + 3] * s.w;
    *(float4*)(ra.news + i) = ns;
  }
}

// ---------------- h = LN(o * tanh(c)) ----------------
__global__ __launch_bounds__(256) void k_ln(const float* __restrict__ o,
                                            const float* __restrict__ tc,
                                            const float* __restrict__ lg,
                                            const float* __restrict__ lb,
                                            float* __restrict__ h) {
  int b = blockIdx.x, tid = threadIdx.x;
  float2 ov = *(const float2*)(o + (size_t)b * 512 + tid * 2);
  float2 tv = *(const float2*)(tc + (size_t)b * 512 + tid * 2);
  float h0 = ov.x * tv.x, h1 = ov.y * tv.y;
  float s = h0 + h1, ss = h0 * h0 + h1 * h1;
#pragma unroll
  for (int off = 32; off; off >>= 1) {
    s += __shfl_xor(s, off);
    ss += __shfl_xor(ss, off);
  }
  __shared__ float red[8];
  int wid = tid >> 6;
  if ((tid & 63) == 0) { red[wid] = s; red[4 + wid] = ss; }
  __syncthreads();
  s = red[0] + red[1] + red[2] + red[3];
  ss = red[4] + red[5] + red[6] + red[7];
  float mu = s * (1.f / 512.f);
  float var = ss * (1.f / 512.f) - mu * mu;
  float rs = rsqrtf(var + 1e-5f);
  int j = tid * 2;
  h[(size_t)b * 512 + j]     = (h0 - mu) * rs * lg[j]     + lb[j];
  h[(size_t)b * 512 + j + 1] = (h1 - mu) * rs * lg[j + 1] + lb[j + 1];
}

// ---------------- launcher ----------------
extern "C" void kernel_launch(void* const* d_in, const int* in_sizes, int n_in,
                              void* d_out, int out_size, void* d_ws, size_t ws_size,
                              hipStream_t stream) {
  const float* x    = (const float*)d_in[0];
  const float* h0   = (const float*)d_in[1];
  const float* c0   = (const float*)d_in[2];
  const float* s0   = (const float*)d_in[3];
  const float* Wk   = (const float*)d_in[4];
  const float* Wr   = (const float*)d_in[5];
  const float* bias = (const float*)d_in[6];
  const float* kx   = (const float*)d_in[7];
  const float* kh   = (const float*)d_in[8];
  const float* tk   = (const float*)d_in[9];
  const float* fc   = (const float*)d_in[10];
  const float* fb   = (const float*)d_in[11];
  const float* aw   = (const float*)d_in[12];
  const float* ab   = (const float*)d_in[13];
  const float* lg   = (const float*)d_in[14];
  const float* lbp  = (const float*)d_in[15];
  float* out = (float*)d_out;
  char* ws = (char*)d_ws;
  auto BF = [&](unsigned long long off) { return (bf16_t*)(ws + off); };
  auto FP = [&](unsigned long long off) { return (float*)(ws + off); };

  k_prep<<<2048, 256, 0, stream>>>(x, h0, s0, fc, BF(O_XHI), BF(O_XLO), BF(O_H0),
                                   BF(O_S0H), BF(O_S0L), BF(O_FCB));
  k_tconv<<<1408, 256, 0, stream>>>(Wk, Wr, aw, kx, kh, BF(O_KT), BF(O_RKT), BF(O_AWT),
                                    BF(O_KXH), BF(O_KXL), BF(O_KHH), BF(O_KHL));

  // fused gates GEMM + cell: c -> d_out[2M..4M), tanh(c) -> TC
  {
    GatesArgs ga{ BF(O_XHI), BF(O_H0), BF(O_KT), BF(O_RKT), bias, c0,
                  out + 2097152, FP(O_TC) };
    k_gates<<<dim3(4, 64), 512, 0, stream>>>(ga);
  }

  // agg GEMM (hi/lo split), output in revolutions
  {
    GArgs g{};
    g.p[0] = { BF(O_XHI), BF(O_KXH), 256, 256, 256 };
    g.p[1] = { BF(O_XHI), BF(O_KXL), 256, 256, 256 };
    g.p[2] = { BF(O_XLO), BF(O_KXH), 256, 256, 256 };
    g.p[3] = { BF(O_S0H), BF(O_KHH), 256, 256, 256 };
    g.p[4] = { BF(O_S0H), BF(O_KHL), 256, 256, 256 };
    g.p[5] = { BF(O_S0L), BF(O_KHH), 256, 256, 256 };
    g.np = 6; g.bias = nullptr; g.act = 0;
    g.out = FP(O_AGG); g.ldout = 256;
    k_gemm<64, 64><<<dim3(4, 64), 512, 0, stream>>>(g);
  }

  // Fourier KAN (q=8 K-split, 256 blocks = 1/CU). P chunks 0-2 overlay
  // XHI/XLO, H0, S0H/S0L (dead after agg GEMM above).
  FArgs fa;
  fa.agg = FP(O_AGG); fa.fcb = BF(O_FCB);
  fa.P[0] = FP(0ull);
  fa.P[1] = FP(4194304ull);
  fa.P[2] = FP(8388608ull);
  for (int c = 3; c < 8; c++) fa.P[c] = FP(O_P3 + (unsigned long long)(c - 3) * 4194304ull);
  k_fourier<<<256, 512, 0, stream>>>(fa);

  // reduce partials, emit new_s (d_out[4M..5M)) + sub_out bf16
  RArgs ra;
  for (int c = 0; c < 8; c++) ra.P[c] = fa.P[c];
  ra.fb = fb; ra.tk = tk; ra.s0 = s0;
  ra.news = out + 4194304; ra.sob = BF(O_SOB);
  k_freduce<<<1024, 256, 0, stream>>>(ra);

  // out-proj GEMM: o = sigmoid(sub_out@agg_w + agg_b)   (O overlays FCB)
  {
    GArgs g{};
    g.p[0] = { BF(O_SOB), BF(O_AWT), 256, 256, 256 };
    g.np = 1; g.bias = ab; g.act = 1;
    g.out = FP(O_O); g.ldout = 512;
    k_gemm<64, 128><<<dim3(4, 64), 512, 0, stream>>>(g);
  }
  // h = LN(o * tanh(c)) -> d_out[0..2M)
  k_ln<<<4096, 256, 0, stream>>>(FP(O_O), FP(O_TC), lg, lbp, out);
}